// Round 14
// baseline (1015.214 us; speedup 1.0000x reference)
//
#include <hip/hip_runtime.h>

#define SQ 1024
#define DIM 1024
#define NH 16
#define HDIM 64
#define FFD 4096
#define NV 51200
#define NL 8
#define LDBUF 5120
#define WELEMS ((long)(3 * DIM + DIM + FFD + FFD) * DIM)

typedef __bf16 bf16x8 __attribute__((ext_vector_type(8)));
typedef float f32x4 __attribute__((ext_vector_type(4)));

__device__ __forceinline__ unsigned short f2bf(float f) {
    union { float f; unsigned int i; } v; v.f = f;
    unsigned int r = v.i + 0x7fffu + ((v.i >> 16) & 1u);
    return (unsigned short)(r >> 16);
}
__device__ __forceinline__ float gelu_tanh(float x) {
    float x3 = x * x * x;
    return 0.5f * x * (1.0f + tanhf(0.79788456080286535588f * (x + 0.044715f * x3)));
}
__device__ __forceinline__ void cvt8(const float* __restrict__ s, unsigned short* __restrict__ d, long i) {
    float4 a = *reinterpret_cast<const float4*>(s + i);
    float4 b = *reinterpret_cast<const float4*>(s + i + 4);
    bf16x8 w;
    w[0] = (__bf16)a.x; w[1] = (__bf16)a.y; w[2] = (__bf16)a.z; w[3] = (__bf16)a.w;
    w[4] = (__bf16)b.x; w[5] = (__bf16)b.y; w[6] = (__bf16)b.z; w[7] = (__bf16)b.w;
    *reinterpret_cast<bf16x8*>(d + i) = w;
}

#define GLD16(gp, lp) __builtin_amdgcn_global_load_lds( \
    (__attribute__((address_space(1))) void*)(gp), \
    (__attribute__((address_space(3))) void*)(lp), 16, 0, 0)
#define VMCNT0 asm volatile("s_waitcnt vmcnt(0)" ::: "memory")

// ---------------- serial-path weight conversion ----------------
__global__ void cvt4_kernel(const float* __restrict__ w0, const float* __restrict__ w1,
                            const float* __restrict__ w2, const float* __restrict__ w3,
                            unsigned short* __restrict__ dst) {
    const int b = blockIdx.x;
    const float* s; long off; unsigned short* d;
    if (b < 1536)      { s = w0; d = dst;                      off = (long)b * 2048; }
    else if (b < 2048) { s = w1; d = dst + (long)3072 * 1024;  off = (long)(b - 1536) * 2048; }
    else if (b < 4096) { s = w2; d = dst + (long)4096 * 1024;  off = (long)(b - 2048) * 2048; }
    else               { s = w3; d = dst + (long)8192 * 1024;  off = (long)(b - 4096) * 2048; }
    cvt8(s, d, off + threadIdx.x * 8);
}
__global__ void cvt_kernel(const float* __restrict__ src, unsigned short* __restrict__ dst) {
    cvt8(src, dst, ((long)blockIdx.x * 256 + threadIdx.x) * 8);
}

// ---------------- sin/cos table ----------------
__global__ void sincos_kernel(const int* __restrict__ pos, float2* __restrict__ sc) {
    const int t = blockIdx.x * 256 + threadIdx.x;
    if (t >= SQ * 16) return;
    const int s = t >> 4, i = t & 15;
    const float ang = (float)pos[s] * powf(10000.0f, -(float)i / 16.0f);
    sc[t] = make_float2(sinf(ang), cosf(ang));
}

// ---------------- embedding gather ----------------
__global__ void embed_kernel(const int* __restrict__ idx, const float* __restrict__ emb,
                             float* __restrict__ x) {
    const int s = blockIdx.x;
    const int d = threadIdx.x * 4;
    const int row = idx[s];
    *reinterpret_cast<float4*>(x + (long)s * DIM + d) =
        *reinterpret_cast<const float4*>(emb + (long)row * DIM + d);
}

// ---------------- fused (residual reduce over 4 split-K parts) + layernorm ----------------
template <bool RED>
__global__ __launch_bounds__(256) void ln_kernel(float* __restrict__ x,
                                                 const float* __restrict__ part,
                                                 const float* __restrict__ w,
                                                 const float* __restrict__ b,
                                                 unsigned short* __restrict__ out) {
    __shared__ float red[8];
    const int s = blockIdx.x, tid = threadIdx.x;
    const long fidx = (long)s * 256 + tid;
    float4 v = reinterpret_cast<const float4*>(x)[fidx];
    if (RED) {
        #pragma unroll
        for (int z = 0; z < 4; z++) {
            float4 p = reinterpret_cast<const float4*>(part + (long)z * SQ * DIM)[fidx];
            v.x += p.x; v.y += p.y; v.z += p.z; v.w += p.w;
        }
        reinterpret_cast<float4*>(x)[fidx] = v;
    }
    float sum = v.x + v.y + v.z + v.w;
    float sq = v.x * v.x + v.y * v.y + v.z * v.z + v.w * v.w;
    #pragma unroll
    for (int off = 32; off; off >>= 1) { sum += __shfl_xor(sum, off); sq += __shfl_xor(sq, off); }
    const int wid = tid >> 6, lane = tid & 63;
    if (lane == 0) { red[wid * 2] = sum; red[wid * 2 + 1] = sq; }
    __syncthreads();
    sum = red[0] + red[2] + red[4] + red[6];
    sq  = red[1] + red[3] + red[5] + red[7];
    const float mu = sum * (1.0f / DIM);
    const float var = sq * (1.0f / DIM) - mu * mu;
    const float rstd = rsqrtf(var + 1e-5f);
    const int d = tid * 4;
    float vv[4] = {v.x, v.y, v.z, v.w};
    ushort4 o;
    unsigned short* op = (unsigned short*)&o;
    #pragma unroll
    for (int j = 0; j < 4; j++)
        op[j] = f2bf((vv[j] - mu) * rstd * w[d + j] + b[d + j]);
    *reinterpret_cast<ushort4*>(out + (long)s * DIM + d) = o;
}

// ---------------- QKV(+RoPE) + fc_in(gelu) GEMM (0..447) + LM cvt chores (448..703) ----------------
__global__ __launch_bounds__(256) void gemm_qkv_fcin(const unsigned short* __restrict__ A,
                                                     const unsigned short* __restrict__ B1,
                                                     const unsigned short* __restrict__ B2,
                                                     const float* __restrict__ bias,
                                                     unsigned short* __restrict__ ffout,
                                                     const float2* __restrict__ sc,
                                                     unsigned short* __restrict__ qt,
                                                     unsigned short* __restrict__ kt,
                                                     unsigned short* __restrict__ vt,
                                                     const float* __restrict__ lmsrc,
                                                     unsigned short* __restrict__ lmdst) {
    __shared__ __align__(16) unsigned short As[2][128 * 64];
    __shared__ __align__(16) unsigned short Bs[2][128 * 64];
    const int tid = threadIdx.x;
    if (blockIdx.x >= 448) {
        if (lmdst) {
            const int cb = (int)blockIdx.x - 448;
            const long stride = (long)((int)gridDim.x - 448) * 256;
            const long nlmv = (long)(NV / NL) * DIM / 8;
            for (long i = (long)cb * 256 + tid; i < nlmv; i += stride) cvt8(lmsrc, lmdst, i * 8);
        }
        return;
    }
    const int sb = (blockIdx.x & 7) * 56 + (blockIdx.x >> 3);
    const int mb = sb & 7, nb = sb >> 3;
    const int m0 = mb * 128, n0 = nb * 128;
    const int lane = tid & 63, wid = tid >> 6;
    const int l15 = lane & 15, lhi = lane >> 4;
    const int wr = wid >> 1, wc = wid & 1;
    const int sw = l15 & 7;

    const unsigned short* Bbase = B1;
    int nloc = n0;
    if (nb >= 24) { Bbase = B2; nloc = n0 - 3072; }

    f32x4 acc[4][4];
    #pragma unroll
    for (int i = 0; i < 4; i++)
        #pragma unroll
        for (int j = 0; j < 4; j++) acc[i][j] = (f32x4){0.f, 0.f, 0.f, 0.f};

    const int wbase = (tid & ~63) * 8;

    auto stage = [&](int buf, int kt_) {
        const int k0 = kt_ << 6;
        #pragma unroll
        for (int i = 0; i < 4; i++) {
            const int e = (i * 256 + tid) * 8;
            const int r = e >> 6;
            const int cs = (((e >> 3) & 7) ^ (r & 7)) * 8;
            GLD16(A + (long)(m0 + r) * DIM + k0 + cs, &As[buf][i * 2048 + wbase]);
        }
        #pragma unroll
        for (int i = 0; i < 4; i++) {
            const int e = (i * 256 + tid) * 8;
            const int r = e >> 6;
            const int cs = (((e >> 3) & 7) ^ (r & 7)) * 8;
            GLD16(Bbase + (long)(nloc + r) * 1024 + k0 + cs, &Bs[buf][i * 2048 + wbase]);
        }
    };
    auto compute = [&](int buf) {
        #pragma unroll
        for (int ks = 0; ks < 2; ks++) {
            bf16x8 af[4], bfr[4];
            #pragma unroll
            for (int mf = 0; mf < 4; mf++)
                af[mf] = *reinterpret_cast<const bf16x8*>(
                    &As[buf][(wr * 64 + mf * 16 + l15) * 64 + ((ks * 4 + lhi) ^ sw) * 8]);
            #pragma unroll
            for (int nf = 0; nf < 4; nf++)
                bfr[nf] = *reinterpret_cast<const bf16x8*>(
                    &Bs[buf][(wc * 64 + nf * 16 + l15) * 64 + ((ks * 4 + lhi) ^ sw) * 8]);
            #pragma unroll
            for (int mf = 0; mf < 4; mf++)
                #pragma unroll
                for (int nf = 0; nf < 4; nf++)
                    acc[mf][nf] = __builtin_amdgcn_mfma_f32_16x16x32_bf16(af[mf], bfr[nf], acc[mf][nf], 0, 0, 0);
        }
    };

    int cur = 0;
    stage(0, 0);
    VMCNT0; __syncthreads();
    for (int kt_ = 0; kt_ < 16; kt_++) {
        if (kt_ + 1 < 16) stage(cur ^ 1, kt_ + 1);
        compute(cur);
        if (kt_ + 1 < 16) { VMCNT0; __syncthreads(); cur ^= 1; }
    }

    if (nb < 24) {
        #pragma unroll
        for (int nf = 0; nf < 4; nf++) {
            const int col = n0 + wc * 64 + nf * 16 + l15;
            const int g = col / 768;
            const int r768 = col - g * 768;
            const int sec = r768 >> 8;
            const int off = r768 & 255;
            const int h = g * 4 + (off >> 6);
            const int d = off & 63;
            const bool isrot = (d < 32);
            const int dodd = d & 1;
            #pragma unroll
            for (int mf = 0; mf < 4; mf++) {
                #pragma unroll
                for (int j = 0; j < 4; j++) {
                    const int row = m0 + wr * 64 + mf * 16 + lhi * 4 + j;
                    float v = acc[mf][nf][j];
                    const float pv = __shfl_xor(v, 1);
                    float outv = v;
                    if (isrot && sec != 1) {
                        const float2 scv = sc[row * 16 + (d >> 1)];
                        outv = dodd ? (v * scv.y + pv * scv.x)
                                    : (v * scv.y - pv * scv.x);
                    }
                    if (sec == 0)      qt[((long)(h * SQ + row)) * HDIM + d] = f2bf(outv);
                    else if (sec == 2) kt[((long)(h * SQ + row)) * HDIM + d] = f2bf(outv);
                    else               vt[(long)h * (HDIM * SQ) + (long)d * SQ + row] = f2bf(outv);
                }
            }
        }
    } else {
        #pragma unroll
        for (int nf = 0; nf < 4; nf++) {
            const int col = n0 + wc * 64 + nf * 16 + l15;
            #pragma unroll
            for (int mf = 0; mf < 4; mf++) {
                #pragma unroll
                for (int j = 0; j < 4; j++) {
                    const int row = m0 + wr * 64 + mf * 16 + lhi * 4 + j;
                    float v = gelu_tanh(acc[mf][nf][j] + bias[col - 3072]);
                    ffout[(long)row * LDBUF + (col - 3072)] = f2bf(v);
                }
            }
        }
    }
}

// ---------------- FUSED: attention (0..255, L2-direct, barrier-free) + fc_out split-K4 (256..511)
//                  + weight chores (512..) ----------------
// attn: K/V fragments read directly from global (L2-resident, zero intra-block reuse so
// staging was pure overhead — guide m169). Only per-wave Ps relayout uses LDS; no barriers.
__global__ __launch_bounds__(256) void attn_fcout(const unsigned short* __restrict__ qt,
                                                  const unsigned short* __restrict__ kt,
                                                  const unsigned short* __restrict__ vt,
                                                  unsigned short* __restrict__ buf,
                                                  const unsigned short* __restrict__ fcw,
                                                  const float* __restrict__ fcb,
                                                  float* __restrict__ parts,
                                                  const float* __restrict__ nw0,
                                                  const float* __restrict__ nw1,
                                                  const float* __restrict__ nw2,
                                                  const float* __restrict__ nw3,
                                                  unsigned short* __restrict__ nd) {
    __shared__ __align__(16) unsigned short smem[32768];
    const int tid = threadIdx.x, lane = tid & 63, wid = tid >> 6;
    const int l15 = lane & 15, lhi = lane >> 4;
    const int sw = l15 & 7;
    const int wbase = (tid & ~63) * 8;

    if (blockIdx.x < 256) {
        // ================= attention (barrier-free) =================
        unsigned short* Psw = smem + wid * 1024;  // per-wave 2 KB
        const int h = blockIdx.x & 15;
        const int qb = 15 - ((int)blockIdx.x >> 4);
        const int q0 = qb * 64 + wid * 16;

        bf16x8 aq[2];
        {
            const unsigned short* qp = qt + ((long)(h * SQ + q0 + l15)) * HDIM;
            aq[0] = *reinterpret_cast<const bf16x8*>(qp + lhi * 8);
            aq[1] = *reinterpret_cast<const bf16x8*>(qp + 32 + lhi * 8);
        }
        f32x4 o[4];
        #pragma unroll
        for (int nf = 0; nf < 4; nf++) o[nf] = (f32x4){0.f, 0.f, 0.f, 0.f};
        float mrow[4] = {-1e30f, -1e30f, -1e30f, -1e30f};
        float lrow[4] = {0.f, 0.f, 0.f, 0.f};

        const unsigned short* kbase = kt + (long)h * SQ * HDIM;
        const unsigned short* vbase = vt + (long)h * (HDIM * SQ);

        for (int kvt = 0; kvt <= qb; kvt++) {
            const int kv0 = kvt * 64;
            f32x4 sa[4];
            #pragma unroll
            for (int hc = 0; hc < 4; hc++) sa[hc] = (f32x4){0.f, 0.f, 0.f, 0.f};
            // QK^T: K fragments direct from global (16B contiguous along HD)
            #pragma unroll
            for (int hc = 0; hc < 4; hc++)
                #pragma unroll
                for (int ks = 0; ks < 2; ks++) {
                    bf16x8 bk = *reinterpret_cast<const bf16x8*>(
                        kbase + (long)(kv0 + hc * 16 + l15) * HDIM + ks * 32 + lhi * 8);
                    sa[hc] = __builtin_amdgcn_mfma_f32_16x16x32_bf16(aq[ks], bk, sa[hc], 0, 0, 0);
                }
            float pr[4][4], mb[4];
            #pragma unroll
            for (int j = 0; j < 4; j++) {
                const int qi = q0 + lhi * 4 + j;
                #pragma unroll
                for (int hc = 0; hc < 4; hc++) {
                    const int ki = kv0 + hc * 16 + l15;
                    const float sv = sa[hc][j] * 0.125f;
                    pr[hc][j] = (ki <= qi) ? sv : -1e30f;
                }
                mb[j] = fmaxf(fmaxf(pr[0][j], pr[1][j]), fmaxf(pr[2][j], pr[3][j]));
            }
            #pragma unroll
            for (int off = 1; off < 16; off <<= 1)
                #pragma unroll
                for (int j = 0; j < 4; j++) mb[j] = fmaxf(mb[j], __shfl_xor(mb[j], off));
            float alpha[4], psum[4];
            #pragma unroll
            for (int j = 0; j < 4; j++) {
                const float mn = fmaxf(mrow[j], mb[j]);
                alpha[j] = __expf(mrow[j] - mn);
                mrow[j] = mn;
                psum[j] = 0.f;
                #pragma unroll
                for (int hc = 0; hc < 4; hc++) { pr[hc][j] = __expf(pr[hc][j] - mn); psum[j] += pr[hc][j]; }
            }
            #pragma unroll
            for (int off = 1; off < 16; off <<= 1)
                #pragma unroll
                for (int j = 0; j < 4; j++) psum[j] += __shfl_xor(psum[j], off);
            #pragma unroll
            for (int j = 0; j < 4; j++) lrow[j] = lrow[j] * alpha[j] + psum[j];
            #pragma unroll
            for (int nf = 0; nf < 4; nf++)
                #pragma unroll
                for (int j = 0; j < 4; j++) o[nf][j] *= alpha[j];
            // P relayout via wave-private LDS (no barrier needed)
            #pragma unroll
            for (int hc = 0; hc < 4; hc++)
                #pragma unroll
                for (int j = 0; j < 4; j++) {
                    const int prow = lhi * 4 + j;
                    const int pc8 = (hc * 2 + (l15 >> 3)) ^ (prow & 7);
                    Psw[prow * 64 + pc8 * 8 + (l15 & 7)] = f2bf(pr[hc][j]);
                }
            bf16x8 ap[2];
            ap[0] = *reinterpret_cast<const bf16x8*>(Psw + l15 * 64 + ((0 + lhi) ^ sw) * 8);
            ap[1] = *reinterpret_cast<const bf16x8*>(Psw + l15 * 64 + ((4 + lhi) ^ sw) * 8);
            // PV: V fragments direct from global (16B contiguous along S)
            #pragma unroll
            for (int nf = 0; nf < 4; nf++)
                #pragma unroll
                for (int ks2 = 0; ks2 < 2; ks2++) {
                    bf16x8 bv = *reinterpret_cast<const bf16x8*>(
                        vbase + (long)(nf * 16 + l15) * SQ + kv0 + ks2 * 32 + lhi * 8);
                    o[nf] = __builtin_amdgcn_mfma_f32_16x16x32_bf16(ap[ks2], bv, o[nf], 0, 0, 0);
                }
        }
        #pragma unroll
        for (int nf = 0; nf < 4; nf++)
            #pragma unroll
            for (int j = 0; j < 4; j++) {
                const int row = q0 + lhi * 4 + j;
                buf[(long)row * LDBUF + h * HDIM + nf * 16 + l15] = f2bf(o[nf][j] / lrow[j]);
            }
    } else if (blockIdx.x < 512) {
        // ================= fc_out GEMM, split-K=4 (16 K-steps) =================
        unsigned short* As0 = smem;
        unsigned short* Bs0 = smem + 16384;
        const int b2 = (int)blockIdx.x - 256;
        const int sb = (b2 & 7) * 32 + (b2 >> 3);
        const int kz = sb & 3, nb = (sb >> 2) & 7, mb = sb >> 5;
        const int m0 = mb * 128, n0 = nb * 128;
        const int kt0 = kz * 16;
        const int wr = wid >> 1, wc = wid & 1;
        const unsigned short* Aff = buf + DIM;

        f32x4 acc[4][4];
        #pragma unroll
        for (int i = 0; i < 4; i++)
            #pragma unroll
            for (int j = 0; j < 4; j++) acc[i][j] = (f32x4){0.f, 0.f, 0.f, 0.f};

        auto stage = [&](int bf_, int kt_) {
            const int k0 = kt_ << 6;
            #pragma unroll
            for (int i = 0; i < 4; i++) {
                const int e = (i * 256 + tid) * 8;
                const int r = e >> 6;
                const int cs = (((e >> 3) & 7) ^ (r & 7)) * 8;
                GLD16(Aff + (long)(m0 + r) * LDBUF + k0 + cs, As0 + bf_ * 8192 + i * 2048 + wbase);
                GLD16(fcw + (long)(n0 + r) * FFD + k0 + cs, Bs0 + bf_ * 8192 + i * 2048 + wbase);
            }
        };
        auto compute = [&](int bf_) {
            #pragma unroll
            for (int ks = 0; ks < 2; ks++) {
                bf16x8 af[4], bfr[4];
                #pragma unroll
                for (int mf = 0; mf < 4; mf++)
                    af[mf] = *reinterpret_cast<const bf16x8*>(
                        As0 + bf_ * 8192 + (wr * 64 + mf * 16 + l15) * 64 + ((ks * 4 + lhi) ^ sw) * 8);
                #pragma unroll
                for (int nf = 0; nf < 4; nf++)
                    bfr[nf] = *reinterpret_cast<const bf16x8*>(
                        Bs0 + bf_ * 8192 + (wc * 64 + nf * 16 + l15) * 64 + ((ks * 4 + lhi) ^ sw) * 8);
                #pragma unroll
                for (int mf = 0; mf < 4; mf++)
                    #pragma unroll
                    for (int nf = 0; nf < 4; nf++)
                        acc[mf][nf] = __builtin_amdgcn_mfma_f32_16x16x32_bf16(af[mf], bfr[nf], acc[mf][nf], 0, 0, 0);
            }
        };

        int cur = 0;
        stage(0, kt0);
        VMCNT0; __syncthreads();
        for (int t = 0; t < 16; t++) {
            if (t + 1 < 16) stage(cur ^ 1, kt0 + t + 1);
            compute(cur);
            if (t + 1 < 16) { VMCNT0; __syncthreads(); cur ^= 1; }
        }

        float* P = parts + (long)kz * SQ * DIM;
        #pragma unroll
        for (int nf = 0; nf < 4; nf++) {
            const int col = n0 + wc * 64 + nf * 16 + l15;
            const float bv = (kz == 0) ? fcb[col] : 0.f;
            #pragma unroll
            for (int mf = 0; mf < 4; mf++) {
                #pragma unroll
                for (int j = 0; j < 4; j++) {
                    const int row = m0 + wr * 64 + mf * 16 + lhi * 4 + j;
                    P[(long)row * DIM + col] = acc[mf][nf][j] + bv;
                }
            }
        }
    } else {
        if (nd) {
            const int cb = (int)blockIdx.x - 512;
            const long stride = (long)((int)gridDim.x - 512) * 256;
            const long base = (long)cb * 256 + tid;
            const long n0v = (long)3072 * 1024 / 8, n1v = (long)1024 * 1024 / 8;
            const long n2v = (long)4096 * 1024 / 8, n3v = (long)4096 * 1024 / 8;
            for (long i = base; i < n0v; i += stride) cvt8(nw0, nd, i * 8);
            unsigned short* d1 = nd + n0v * 8;
            for (long i = base; i < n1v; i += stride) cvt8(nw1, d1, i * 8);
            unsigned short* d2 = d1 + n1v * 8;
            for (long i = base; i < n2v; i += stride) cvt8(nw2, d2, i * 8);
            unsigned short* d3 = d2 + n2v * 8;
            for (long i = base; i < n3v; i += stride) cvt8(nw3, d3, i * 8);
        }
    }
}

// ---------------- Wo GEMM (K=1024), split-K=4, RMW into parts[0..3] ----------------
__global__ __launch_bounds__(256) void wo_rmw(const unsigned short* __restrict__ buf,
                                              const unsigned short* __restrict__ wo,
                                              float* __restrict__ parts) {
    __shared__ __align__(16) unsigned short As[2][128 * 64];
    __shared__ __align__(16) unsigned short Bs[2][128 * 64];
    const int tid = threadIdx.x;
    const int sb = (blockIdx.x & 7) * 32 + (blockIdx.x >> 3);
    const int kz = sb & 3, nb = (sb >> 2) & 7, mb = sb >> 5;
    const int m0 = mb * 128, n0 = nb * 128;
    const int kt0 = kz * 4;
    const int lane = tid & 63, wid = tid >> 6;
    const int l15 = lane & 15, lhi = lane >> 4;
    const int wr = wid >> 1, wc = wid & 1;
    const int sw = l15 & 7;
    const int wbase = (tid & ~63) * 8;

    f32x4 acc[4][4];
    #pragma unroll
    for (int i = 0; i < 4; i++)
        #pragma unroll
        for (int j = 0; j < 4; j++) acc[i][j] = (f32x4){0.f, 0.f, 0.f, 0.f};

    auto stage = [&](int bf_, int kt_) {
        const int k0 = kt_ << 6;
        #pragma unroll
        for (int i = 0; i < 4; i++) {
            const int e = (i * 256 + tid) * 8;
            const int r = e >> 6;
            const int cs = (((e >> 3) & 7) ^ (r & 7)) * 8;
            GLD16(buf + (long)(m0 + r) * LDBUF + k0 + cs, &As[bf_][i * 2048 + wbase]);
            GLD16(wo + (long)(n0 + r) * DIM + k0 + cs, &Bs[bf_][i * 2048 + wbase]);
        }
    };
    auto compute = [&](int bf_) {
        #pragma unroll
        for (int ks = 0; ks < 2; ks++) {
            bf16x8 af[4], bfr[4];
            #pragma unroll
            for (int mf = 0; mf < 4; mf++)
                af[mf] = *reinterpret_cast<const bf16x8*>(
                    &As[bf_][(wr * 64 + mf * 16 + l15) * 64 + ((ks * 4 + lhi) ^ sw) * 8]);
            #pragma unroll
            for (int nf = 0; nf < 4; nf++)
                bfr[nf] = *reinterpret_cast<const bf16x8*>(
                    &Bs[bf_][(wc * 64 + nf * 16 + l15) * 64 + ((ks * 4 + lhi) ^ sw) * 8]);
            #pragma unroll
            for (int mf = 0; mf < 4; mf++)
                #pragma unroll
                for (int nf = 0; nf < 4; nf++)
                    acc[mf][nf] = __builtin_amdgcn_mfma_f32_16x16x32_bf16(af[mf], bfr[nf], acc[mf][nf], 0, 0, 0);
        }
    };

    int cur = 0;
    stage(0, kt0);
    VMCNT0; __syncthreads();
    for (int t = 0; t < 4; t++) {
        if (t + 1 < 4) stage(cur ^ 1, kt0 + t + 1);
        compute(cur);
        if (t + 1 < 4) { VMCNT0; __syncthreads(); cur ^= 1; }
    }

    float* P = parts + (long)kz * SQ * DIM;
    #pragma unroll
    for (int nf = 0; nf < 4; nf++) {
        const int col = n0 + wc * 64 + nf * 16 + l15;
        #pragma unroll
        for (int mf = 0; mf < 4; mf++) {
            #pragma unroll
            for (int j = 0; j < 4; j++) {
                const int row = m0 + wr * 64 + mf * 16 + lhi * 4 + j;
                P[(long)row * DIM + col] += acc[mf][nf][j];
            }
        }
    }
}

// ---------------- LM head: 256x256 8-phase (verified r13: 669 TF vs 547 2-phase) ----------------
__global__ __launch_bounds__(512) void gemm256p8(const unsigned short* __restrict__ A,
                                                 const unsigned short* __restrict__ B,
                                                 const float* __restrict__ bias,
                                                 float* __restrict__ C) {
    __shared__ __align__(16) unsigned short As[2][2][128 * 64];
    __shared__ __align__(16) unsigned short Bs[2][2][128 * 64];
    const int tid = threadIdx.x;
    const int nwg = gridDim.x, qch = nwg >> 3;
    const int sb = (blockIdx.x & 7) * qch + (blockIdx.x >> 3);
    const int mb = sb & 3, nb = sb >> 2;
    const int m0 = mb * 256, n0 = nb * 256;
    const int lane = tid & 63, wid = tid >> 6;
    const int l15 = lane & 15, lhi = lane >> 4;
    const int wm = wid >> 2, wn = wid & 3;
    const int sw = l15 & 7;
    const int wbase = (tid & ~63) * 8;

    f32x4 acc[8][4];
    #pragma unroll
    for (int i = 0; i < 8; i++)
        #pragma unroll
        for (int j = 0; j < 4; j++) acc[i][j] = (f32x4){0.f, 0.f, 0.f, 0.f};

    auto stageA = [&](int kt, int hh) {
        const int k0 = kt << 6;
        unsigned short* dst = &As[kt & 1][hh][0];
        #pragma unroll
        for (int i = 0; i < 2; i++) {
            const int e = (i * 512 + tid) * 8;
            const int r = e >> 6;
            const int cs = (((e >> 3) & 7) ^ (r & 7)) * 8;
            GLD16(A + (long)(m0 + hh * 128 + r) * 1024 + k0 + cs, dst + i * 4096 + wbase);
        }
    };
    auto stageB = [&](int kt, int hh) {
        const int k0 = kt << 6;
        unsigned short* dst = &Bs[kt & 1][hh][0];
        #pragma unroll
        for (int i = 0; i < 2; i++) {
            const int e = (i * 512 + tid) * 8;
            const int r = e >> 6;
            const int cs = (((e >> 3) & 7) ^ (r & 7)) * 8;
            GLD16(B + (long)(n0 + hh * 128 + r) * 1024 + k0 + cs, dst + i * 4096 + wbase);
        }
    };

    bf16x8 afA[4][2], bf0[2][2], bf1[2][2];
    auto ldA = [&](int buf, int hh) {
        #pragma unroll
        for (int mi = 0; mi < 4; mi++) {
            const int row = wm * 64 + mi * 16 + l15;
            #pragma unroll
            for (int ks = 0; ks < 2; ks++)
                afA[mi][ks] = *reinterpret_cast<const bf16x8*>(
                    &As[buf][hh][row * 64 + (((ks * 4 + lhi) ^ sw) * 8)]);
        }
    };
    auto ldB = [&](int buf, int hh, bf16x8 (&bfr)[2][2]) {
        #pragma unroll
        for (int ni = 0; ni < 2; ni++) {
            const int row = wn * 32 + ni * 16 + l15;
            #pragma unroll
            for (int ks = 0; ks < 2; ks++)
                bfr[ni][ks] = *reinterpret_cast<const bf16x8*>(
                    &Bs[buf][hh][row * 64 + (((ks * 4 + lhi) ^ sw) * 8)]);
        }
    };
    auto mfma16 = [&](int mh, int nh, bf16x8 (&bfr)[2][2]) {
        __builtin_amdgcn_s_setprio(1);
        #pragma unroll
        for (int mi = 0; mi < 4; mi++)
            #pragma unroll
            for (int ni = 0; ni < 2; ni++)
                #pragma unroll
                for (int ks = 0; ks < 2; ks++)
                    acc[mh * 4 + mi][nh * 2 + ni] = __builtin_amdgcn_mfma_f32_16x16x32_bf16(
                        afA[mi][ks], bfr[ni][ks], acc[mh * 4 + mi][nh * 2 + ni], 0, 0, 0);
        __builtin_amdgcn_s_setprio(0);
    };

#define BAR()   __builtin_amdgcn_s_barrier()
#define LGKM()  asm volatile("s_waitcnt lgkmcnt(0)" ::: "memory")
#define VM6()   asm volatile("s_waitcnt vmcnt(6)" ::: "memory")

    stageA(0, 0); stageB(0, 0); stageB(0, 1); stageA(0, 1);
    stageA(1, 0); stageB(1, 0); stageB(1, 1);
    VM6();
    BAR();

    for (int it = 0; it < 8; it++) {
        const int e = 2 * it, o = 2 * it + 1;
        const bool more = (it + 1 < 8);
        ldA(0, 0); ldB(0, 0, bf0);
        stageA(o, 1);
        BAR(); LGKM(); mfma16(0, 0, bf0); BAR();
        ldB(0, 1, bf1);
        if (more) stageA(e + 2, 0);
        BAR(); LGKM(); mfma16(0, 1, bf1); BAR();
        ldA(0, 1);
        if (more) stageB(e + 2, 0);
        BAR(); LGKM(); mfma16(1, 1, bf1); BAR();
        if (more) stageB(e + 2, 1);
        if (more) { VM6(); } else { VMCNT0; }
        BAR(); LGKM(); mfma16(1, 0, bf0); BAR();
        ldA(1, 0); ldB(1, 0, bf0);
        if (more) stageA(e + 2, 1);
        BAR(); LGKM(); mfma16(0, 0, bf0); BAR();
        ldB(1, 1, bf1);
        if (more) stageA(o + 2, 0);
        BAR(); LGKM(); mfma16(0, 1, bf1); BAR();
        ldA(1, 1);
        if (more) stageB(o + 2, 0);
        BAR(); LGKM(); mfma16(1, 1, bf1); BAR();
        if (more) { stageB(o + 2, 1); VM6(); }
        BAR(); LGKM(); mfma16(1, 0, bf0); BAR();
    }
#undef BAR
#undef LGKM
#undef VM6

    #pragma unroll
    for (int nf = 0; nf < 4; nf++) {
        const int col = n0 + (nf < 2 ? wn * 32 + nf * 16 : 128 + wn * 32 + (nf - 2) * 16) + l15;
        const float bv = bias[col];
        #pragma unroll
        for (int mf = 0; mf < 8; mf++) {
            const int rowb = m0 + (mf < 4 ? wm * 64 + mf * 16 : 128 + wm * 64 + (mf - 4) * 16) + lhi * 4;
            #pragma unroll
            for (int j = 0; j < 4; j++)
                C[(long)(rowb + j) * NV + col] = acc[mf][nf][j] + bv;
        }
    }
}

extern "C" void kernel_launch(void* const* d_in, const int* in_sizes, int n_in,
                              void* d_out, int out_size, void* d_ws, size_t ws_size,
                              hipStream_t stream) {
    const int* idx    = (const int*)d_in[0];
    const int* pos    = (const int*)d_in[1];
    const float* emb  = (const float*)d_in[2];
    const float* Wqkv = (const float*)d_in[3];
    const float* Wo   = (const float*)d_in[4];
    const float* ln1w = (const float*)d_in[5];
    const float* ln1b = (const float*)d_in[6];
    const float* fciw = (const float*)d_in[7];
    const float* fcib = (const float*)d_in[8];
    const float* fcow = (const float*)d_in[9];
    const float* fcob = (const float*)d_in[10];
    const float* lnfw = (const float*)d_in[11];
    const float* lnfb = (const float*)d_in[12];
    const float* lmw  = (const float*)d_in[13];
    const float* lmb  = (const float*)d_in[14];

    const long tailBytes = (long)SQ * DIM * 4 + (long)4 * SQ * DIM * 4 + (long)SQ * DIM * 2
                         + (long)3 * NH * SQ * HDIM * 2 + (long)SQ * LDBUF * 2 + (long)SQ * 16 * 8;
    const long bigBytes  = 2 * WELEMS * 2 + (long)NV * DIM * 2 + tailBytes;
    const bool big = (long)ws_size >= bigBytes + (1 << 20);

    char* ws = (char*)d_ws;
    unsigned short *wbufA, *wbufB, *lmbuf;
    if (big) {
        wbufA = (unsigned short*)ws; ws += WELEMS * 2;
        wbufB = (unsigned short*)ws; ws += WELEMS * 2;
        lmbuf = (unsigned short*)ws; ws += (long)NV * DIM * 2;
    } else {
        wbufA = (unsigned short*)ws; ws += (long)NV * DIM * 2;
        wbufB = wbufA;
        lmbuf = wbufA;
    }
    float* x           = (float*)ws;          ws += (long)SQ * DIM * 4;
    float* parts       = (float*)ws;          ws += (long)4 * SQ * DIM * 4;
    unsigned short* h  = (unsigned short*)ws; ws += (long)SQ * DIM * 2;
    unsigned short* qt = (unsigned short*)ws; ws += (long)NH * SQ * HDIM * 2;
    unsigned short* kt = (unsigned short*)ws; ws += (long)NH * SQ * HDIM * 2;
    unsigned short* vt = (unsigned short*)ws; ws += (long)NH * SQ * HDIM * 2;
    unsigned short* buf= (unsigned short*)ws; ws += (long)SQ * LDBUF * 2;
    float2* sc         = (float2*)ws;         ws += (long)SQ * 16 * 8;

    auto wq = [&](unsigned short* wb) { return wb; };
    auto wo_ = [&](unsigned short* wb) { return wb + (long)3072 * 1024; };
    auto wfi = [&](unsigned short* wb) { return wb + (long)4096 * 1024; };
    auto wfo = [&](unsigned short* wb) { return wb + (long)8192 * 1024; };

    sincos_kernel<<<64, 256, 0, stream>>>(pos, sc);
    embed_kernel<<<SQ, 256, 0, stream>>>(idx, emb, x);
    cvt4_kernel<<<6144, 256, 0, stream>>>(Wqkv, Wo, fciw, fcow, wbufA);

    for (int l = 0; l < NL; l++) {
        unsigned short* wb = (l & 1) ? wbufB : wbufA;
        unsigned short* wn = (l & 1) ? wbufA : wbufB;

        if (!big && l > 0)
            cvt4_kernel<<<6144, 256, 0, stream>>>(Wqkv + (long)l * 3 * DIM * DIM,
                                                  Wo   + (long)l * DIM * DIM,
                                                  fciw + (long)l * FFD * DIM,
                                                  fcow + (long)l * DIM * FFD, wb);

        if (l == 0) ln_kernel<false><<<SQ, 256, 0, stream>>>(x, nullptr, ln1w, ln1b, h);
        else ln_kernel<true><<<SQ, 256, 0, stream>>>(x, parts, ln1w + (long)l * DIM, ln1b + (long)l * DIM, h);

        gemm_qkv_fcin<<<704, 256, 0, stream>>>(h, wq(wb), wfi(wb), fcib + (long)l * FFD,
                                               buf + DIM, sc, qt, kt, vt,
                                               big ? lmw + (long)l * (NV / NL) * DIM : nullptr,
                                               big ? lmbuf + (long)l * (NV / NL) * DIM : nullptr);
        if (big) {
            const int nl = l + 1;
            attn_fcout<<<1024, 256, 0, stream>>>(qt, kt, vt, buf, wfo(wb),
                                                 fcob + (long)l * DIM, parts,
                                                 (nl < NL) ? Wqkv + (long)nl * 3 * DIM * DIM : nullptr,
                                                 (nl < NL) ? Wo   + (long)nl * DIM * DIM : nullptr,
                                                 (nl < NL) ? fciw + (long)nl * FFD * DIM : nullptr,
                                                 (nl < NL) ? fcow + (long)nl * DIM * FFD : nullptr,
                                                 (nl < NL) ? wn : nullptr);
        } else {
            attn_fcout<<<512, 256, 0, stream>>>(qt, kt, vt, buf, wfo(wb),
                                                fcob + (long)l * DIM, parts,
                                                nullptr, nullptr, nullptr, nullptr, nullptr);
        }
        wo_rmw<<<256, 256, 0, stream>>>(buf, wo_(wb), parts);
    }
    if (!big) cvt_kernel<<<25600, 256, 0, stream>>>(lmw, lmbuf);
    ln_kernel<true><<<SQ, 256, 0, stream>>>(x, parts, lnfw, lnfb, h);
    // full 8-phase LM head (verified faster than 2-phase in r13 in-run A/B)
    gemm256p8<<<800, 512, 0, stream>>>(h, lmbuf, lmb, (float*)d_out);
}

// Round 15
// 974.809 us; speedup vs baseline: 1.0414x; 1.0414x over previous
//
#include <hip/hip_runtime.h>

#define SQ 1024
#define DIM 1024
#define NH 16
#define HDIM 64
#define FFD 4096
#define NV 51200
#define NL 8
#define LDBUF 5120
#define WELEMS ((long)(3 * DIM + DIM + FFD + FFD) * DIM)

typedef __bf16 bf16x8 __attribute__((ext_vector_type(8)));
typedef float f32x4 __attribute__((ext_vector_type(4)));

__device__ __forceinline__ unsigned short f2bf(float f) {
    union { float f; unsigned int i; } v; v.f = f;
    unsigned int r = v.i + 0x7fffu + ((v.i >> 16) & 1u);
    return (unsigned short)(r >> 16);
}
__device__ __forceinline__ float gelu_tanh(float x) {
    float x3 = x * x * x;
    return 0.5f * x * (1.0f + tanhf(0.79788456080286535588f * (x + 0.044715f * x3)));
}
__device__ __forceinline__ void cvt8(const float* __restrict__ s, unsigned short* __restrict__ d, long i) {
    float4 a = *reinterpret_cast<const float4*>(s + i);
    float4 b = *reinterpret_cast<const float4*>(s + i + 4);
    bf16x8 w;
    w[0] = (__bf16)a.x; w[1] = (__bf16)a.y; w[2] = (__bf16)a.z; w[3] = (__bf16)a.w;
    w[4] = (__bf16)b.x; w[5] = (__bf16)b.y; w[6] = (__bf16)b.z; w[7] = (__bf16)b.w;
    *reinterpret_cast<bf16x8*>(d + i) = w;
}

#define GLD16(gp, lp) __builtin_amdgcn_global_load_lds( \
    (__attribute__((address_space(1))) void*)(gp), \
    (__attribute__((address_space(3))) void*)(lp), 16, 0, 0)
#define VMCNT0 asm volatile("s_waitcnt vmcnt(0)" ::: "memory")

// ---------------- serial-path weight conversion ----------------
__global__ void cvt4_kernel(const float* __restrict__ w0, const float* __restrict__ w1,
                            const float* __restrict__ w2, const float* __restrict__ w3,
                            unsigned short* __restrict__ dst) {
    const int b = blockIdx.x;
    const float* s; long off; unsigned short* d;
    if (b < 1536)      { s = w0; d = dst;                      off = (long)b * 2048; }
    else if (b < 2048) { s = w1; d = dst + (long)3072 * 1024;  off = (long)(b - 1536) * 2048; }
    else if (b < 4096) { s = w2; d = dst + (long)4096 * 1024;  off = (long)(b - 2048) * 2048; }
    else               { s = w3; d = dst + (long)8192 * 1024;  off = (long)(b - 4096) * 2048; }
    cvt8(s, d, off + threadIdx.x * 8);
}
__global__ void cvt_kernel(const float* __restrict__ src, unsigned short* __restrict__ dst) {
    cvt8(src, dst, ((long)blockIdx.x * 256 + threadIdx.x) * 8);
}

// ---------------- sin/cos table ----------------
__global__ void sincos_kernel(const int* __restrict__ pos, float2* __restrict__ sc) {
    const int t = blockIdx.x * 256 + threadIdx.x;
    if (t >= SQ * 16) return;
    const int s = t >> 4, i = t & 15;
    const float ang = (float)pos[s] * powf(10000.0f, -(float)i / 16.0f);
    sc[t] = make_float2(sinf(ang), cosf(ang));
}

// ---------------- embedding gather ----------------
__global__ void embed_kernel(const int* __restrict__ idx, const float* __restrict__ emb,
                             float* __restrict__ x) {
    const int s = blockIdx.x;
    const int d = threadIdx.x * 4;
    const int row = idx[s];
    *reinterpret_cast<float4*>(x + (long)s * DIM + d) =
        *reinterpret_cast<const float4*>(emb + (long)row * DIM + d);
}

// ---------------- fused (residual reduce over 4 split-K parts) + layernorm ----------------
template <bool RED>
__global__ __launch_bounds__(256) void ln_kernel(float* __restrict__ x,
                                                 const float* __restrict__ part,
                                                 const float* __restrict__ w,
                                                 const float* __restrict__ b,
                                                 unsigned short* __restrict__ out) {
    __shared__ float red[8];
    const int s = blockIdx.x, tid = threadIdx.x;
    const long fidx = (long)s * 256 + tid;
    float4 v = reinterpret_cast<const float4*>(x)[fidx];
    if (RED) {
        #pragma unroll
        for (int z = 0; z < 4; z++) {
            float4 p = reinterpret_cast<const float4*>(part + (long)z * SQ * DIM)[fidx];
            v.x += p.x; v.y += p.y; v.z += p.z; v.w += p.w;
        }
        reinterpret_cast<float4*>(x)[fidx] = v;
    }
    float sum = v.x + v.y + v.z + v.w;
    float sq = v.x * v.x + v.y * v.y + v.z * v.z + v.w * v.w;
    #pragma unroll
    for (int off = 32; off; off >>= 1) { sum += __shfl_xor(sum, off); sq += __shfl_xor(sq, off); }
    const int wid = tid >> 6, lane = tid & 63;
    if (lane == 0) { red[wid * 2] = sum; red[wid * 2 + 1] = sq; }
    __syncthreads();
    sum = red[0] + red[2] + red[4] + red[6];
    sq  = red[1] + red[3] + red[5] + red[7];
    const float mu = sum * (1.0f / DIM);
    const float var = sq * (1.0f / DIM) - mu * mu;
    const float rstd = rsqrtf(var + 1e-5f);
    const int d = tid * 4;
    float vv[4] = {v.x, v.y, v.z, v.w};
    ushort4 o;
    unsigned short* op = (unsigned short*)&o;
    #pragma unroll
    for (int j = 0; j < 4; j++)
        op[j] = f2bf((vv[j] - mu) * rstd * w[d + j] + b[d + j]);
    *reinterpret_cast<ushort4*>(out + (long)s * DIM + d) = o;
}

// ---------------- QKV(+RoPE) + fc_in(gelu) GEMM (0..447) + LM cvt chores (448..703) ----------------
__global__ __launch_bounds__(256) void gemm_qkv_fcin(const unsigned short* __restrict__ A,
                                                     const unsigned short* __restrict__ B1,
                                                     const unsigned short* __restrict__ B2,
                                                     const float* __restrict__ bias,
                                                     unsigned short* __restrict__ ffout,
                                                     const float2* __restrict__ sc,
                                                     unsigned short* __restrict__ qt,
                                                     unsigned short* __restrict__ kt,
                                                     unsigned short* __restrict__ vt,
                                                     const float* __restrict__ lmsrc,
                                                     unsigned short* __restrict__ lmdst) {
    __shared__ __align__(16) unsigned short As[2][128 * 64];
    __shared__ __align__(16) unsigned short Bs[2][128 * 64];
    const int tid = threadIdx.x;
    if (blockIdx.x >= 448) {
        if (lmdst) {
            const int cb = (int)blockIdx.x - 448;
            const long stride = (long)((int)gridDim.x - 448) * 256;
            const long nlmv = (long)(NV / NL) * DIM / 8;
            for (long i = (long)cb * 256 + tid; i < nlmv; i += stride) cvt8(lmsrc, lmdst, i * 8);
        }
        return;
    }
    const int sb = (blockIdx.x & 7) * 56 + (blockIdx.x >> 3);
    const int mb = sb & 7, nb = sb >> 3;
    const int m0 = mb * 128, n0 = nb * 128;
    const int lane = tid & 63, wid = tid >> 6;
    const int l15 = lane & 15, lhi = lane >> 4;
    const int wr = wid >> 1, wc = wid & 1;
    const int sw = l15 & 7;

    const unsigned short* Bbase = B1;
    int nloc = n0;
    if (nb >= 24) { Bbase = B2; nloc = n0 - 3072; }

    f32x4 acc[4][4];
    #pragma unroll
    for (int i = 0; i < 4; i++)
        #pragma unroll
        for (int j = 0; j < 4; j++) acc[i][j] = (f32x4){0.f, 0.f, 0.f, 0.f};

    const int wbase = (tid & ~63) * 8;

    auto stage = [&](int buf, int kt_) {
        const int k0 = kt_ << 6;
        #pragma unroll
        for (int i = 0; i < 4; i++) {
            const int e = (i * 256 + tid) * 8;
            const int r = e >> 6;
            const int cs = (((e >> 3) & 7) ^ (r & 7)) * 8;
            GLD16(A + (long)(m0 + r) * DIM + k0 + cs, &As[buf][i * 2048 + wbase]);
        }
        #pragma unroll
        for (int i = 0; i < 4; i++) {
            const int e = (i * 256 + tid) * 8;
            const int r = e >> 6;
            const int cs = (((e >> 3) & 7) ^ (r & 7)) * 8;
            GLD16(Bbase + (long)(nloc + r) * 1024 + k0 + cs, &Bs[buf][i * 2048 + wbase]);
        }
    };
    auto compute = [&](int buf) {
        #pragma unroll
        for (int ks = 0; ks < 2; ks++) {
            bf16x8 af[4], bfr[4];
            #pragma unroll
            for (int mf = 0; mf < 4; mf++)
                af[mf] = *reinterpret_cast<const bf16x8*>(
                    &As[buf][(wr * 64 + mf * 16 + l15) * 64 + ((ks * 4 + lhi) ^ sw) * 8]);
            #pragma unroll
            for (int nf = 0; nf < 4; nf++)
                bfr[nf] = *reinterpret_cast<const bf16x8*>(
                    &Bs[buf][(wc * 64 + nf * 16 + l15) * 64 + ((ks * 4 + lhi) ^ sw) * 8]);
            #pragma unroll
            for (int mf = 0; mf < 4; mf++)
                #pragma unroll
                for (int nf = 0; nf < 4; nf++)
                    acc[mf][nf] = __builtin_amdgcn_mfma_f32_16x16x32_bf16(af[mf], bfr[nf], acc[mf][nf], 0, 0, 0);
        }
    };

    int cur = 0;
    stage(0, 0);
    VMCNT0; __syncthreads();
    for (int kt_ = 0; kt_ < 16; kt_++) {
        if (kt_ + 1 < 16) stage(cur ^ 1, kt_ + 1);
        compute(cur);
        if (kt_ + 1 < 16) { VMCNT0; __syncthreads(); cur ^= 1; }
    }

    if (nb < 24) {
        #pragma unroll
        for (int nf = 0; nf < 4; nf++) {
            const int col = n0 + wc * 64 + nf * 16 + l15;
            const int g = col / 768;
            const int r768 = col - g * 768;
            const int sec = r768 >> 8;
            const int off = r768 & 255;
            const int h = g * 4 + (off >> 6);
            const int d = off & 63;
            const bool isrot = (d < 32);
            const int dodd = d & 1;
            #pragma unroll
            for (int mf = 0; mf < 4; mf++) {
                #pragma unroll
                for (int j = 0; j < 4; j++) {
                    const int row = m0 + wr * 64 + mf * 16 + lhi * 4 + j;
                    float v = acc[mf][nf][j];
                    const float pv = __shfl_xor(v, 1);
                    float outv = v;
                    if (isrot && sec != 1) {
                        const float2 scv = sc[row * 16 + (d >> 1)];
                        outv = dodd ? (v * scv.y + pv * scv.x)
                                    : (v * scv.y - pv * scv.x);
                    }
                    if (sec == 0)      qt[((long)(h * SQ + row)) * HDIM + d] = f2bf(outv);
                    else if (sec == 2) kt[((long)(h * SQ + row)) * HDIM + d] = f2bf(outv);
                    else               vt[(long)h * (HDIM * SQ) + (long)d * SQ + row] = f2bf(outv);
                }
            }
        }
    } else {
        #pragma unroll
        for (int nf = 0; nf < 4; nf++) {
            const int col = n0 + wc * 64 + nf * 16 + l15;
            #pragma unroll
            for (int mf = 0; mf < 4; mf++) {
                #pragma unroll
                for (int j = 0; j < 4; j++) {
                    const int row = m0 + wr * 64 + mf * 16 + lhi * 4 + j;
                    float v = gelu_tanh(acc[mf][nf][j] + bias[col - 3072]);
                    ffout[(long)row * LDBUF + (col - 3072)] = f2bf(v);
                }
            }
        }
    }
}

// ---------------- FUSED: attention (0..255, STAGED dbuf — r13 verified) + fc_out split-K4 (256..511)
//                  + weight chores (512..) ----------------
// r14 lesson: L2-direct attn regressed ~38us — global_load_lds dbuf is the latency-hiding
// pipeline (prefetch tile t+1 during tile t MFMA), not a reuse cache. Reverted to r13.
__global__ __launch_bounds__(256) void attn_fcout(const unsigned short* __restrict__ qt,
                                                  const unsigned short* __restrict__ kt,
                                                  const unsigned short* __restrict__ vt,
                                                  unsigned short* __restrict__ buf,
                                                  const unsigned short* __restrict__ fcw,
                                                  const float* __restrict__ fcb,
                                                  float* __restrict__ parts,
                                                  const float* __restrict__ nw0,
                                                  const float* __restrict__ nw1,
                                                  const float* __restrict__ nw2,
                                                  const float* __restrict__ nw3,
                                                  unsigned short* __restrict__ nd) {
    __shared__ __align__(16) unsigned short smem[32768];
    const int tid = threadIdx.x, lane = tid & 63, wid = tid >> 6;
    const int l15 = lane & 15, lhi = lane >> 4;
    const int sw = l15 & 7;
    const int wbase = (tid & ~63) * 8;

    if (blockIdx.x < 256) {
        unsigned short* Ks0 = smem;
        unsigned short* Vs0 = smem + 8192;
        unsigned short* Psw = smem + 16384 + wid * 1024;
        const int h = blockIdx.x & 15;
        const int qb = 15 - ((int)blockIdx.x >> 4);
        const int q0 = qb * 64 + wid * 16;

        bf16x8 aq[2];
        {
            const unsigned short* qp = qt + ((long)(h * SQ + q0 + l15)) * HDIM;
            aq[0] = *reinterpret_cast<const bf16x8*>(qp + lhi * 8);
            aq[1] = *reinterpret_cast<const bf16x8*>(qp + 32 + lhi * 8);
        }
        f32x4 o[4];
        #pragma unroll
        for (int nf = 0; nf < 4; nf++) o[nf] = (f32x4){0.f, 0.f, 0.f, 0.f};
        float mrow[4] = {-1e30f, -1e30f, -1e30f, -1e30f};
        float lrow[4] = {0.f, 0.f, 0.f, 0.f};

        auto stageKV = [&](int b, int kv0) {
            #pragma unroll
            for (int i = 0; i < 2; i++) {
                const int e = (i * 256 + tid) * 8;
                const int r = e >> 6;
                const int cs = (((e >> 3) & 7) ^ (r & 7)) * 8;
                GLD16(kt + ((long)(h * SQ + kv0 + r)) * HDIM + cs, Ks0 + b * 4096 + i * 2048 + wbase);
                GLD16(vt + (long)h * (HDIM * SQ) + (long)r * SQ + kv0 + cs, Vs0 + b * 4096 + i * 2048 + wbase);
            }
        };

        int cur = 0;
        stageKV(0, 0);
        VMCNT0; __syncthreads();
        for (int kvt = 0; kvt <= qb; kvt++) {
            const int kv0 = kvt * 64;
            if (kvt < qb) stageKV(cur ^ 1, kv0 + 64);

            f32x4 sa[4];
            #pragma unroll
            for (int hc = 0; hc < 4; hc++) sa[hc] = (f32x4){0.f, 0.f, 0.f, 0.f};
            #pragma unroll
            for (int hc = 0; hc < 4; hc++)
                #pragma unroll
                for (int ks = 0; ks < 2; ks++) {
                    bf16x8 bk = *reinterpret_cast<const bf16x8*>(
                        Ks0 + cur * 4096 + (hc * 16 + l15) * 64 + ((ks * 4 + lhi) ^ sw) * 8);
                    sa[hc] = __builtin_amdgcn_mfma_f32_16x16x32_bf16(aq[ks], bk, sa[hc], 0, 0, 0);
                }
            float pr[4][4], mb[4];
            #pragma unroll
            for (int j = 0; j < 4; j++) {
                const int qi = q0 + lhi * 4 + j;
                #pragma unroll
                for (int hc = 0; hc < 4; hc++) {
                    const int ki = kv0 + hc * 16 + l15;
                    const float sv = sa[hc][j] * 0.125f;
                    pr[hc][j] = (ki <= qi) ? sv : -1e30f;
                }
                mb[j] = fmaxf(fmaxf(pr[0][j], pr[1][j]), fmaxf(pr[2][j], pr[3][j]));
            }
            #pragma unroll
            for (int off = 1; off < 16; off <<= 1)
                #pragma unroll
                for (int j = 0; j < 4; j++) mb[j] = fmaxf(mb[j], __shfl_xor(mb[j], off));
            float alpha[4], psum[4];
            #pragma unroll
            for (int j = 0; j < 4; j++) {
                const float mn = fmaxf(mrow[j], mb[j]);
                alpha[j] = __expf(mrow[j] - mn);
                mrow[j] = mn;
                psum[j] = 0.f;
                #pragma unroll
                for (int hc = 0; hc < 4; hc++) { pr[hc][j] = __expf(pr[hc][j] - mn); psum[j] += pr[hc][j]; }
            }
            #pragma unroll
            for (int off = 1; off < 16; off <<= 1)
                #pragma unroll
                for (int j = 0; j < 4; j++) psum[j] += __shfl_xor(psum[j], off);
            #pragma unroll
            for (int j = 0; j < 4; j++) lrow[j] = lrow[j] * alpha[j] + psum[j];
            #pragma unroll
            for (int nf = 0; nf < 4; nf++)
                #pragma unroll
                for (int j = 0; j < 4; j++) o[nf][j] *= alpha[j];
            #pragma unroll
            for (int hc = 0; hc < 4; hc++)
                #pragma unroll
                for (int j = 0; j < 4; j++) {
                    const int prow = lhi * 4 + j;
                    const int pc8 = (hc * 2 + (l15 >> 3)) ^ (prow & 7);
                    Psw[prow * 64 + pc8 * 8 + (l15 & 7)] = f2bf(pr[hc][j]);
                }
            bf16x8 ap[2];
            ap[0] = *reinterpret_cast<const bf16x8*>(Psw + l15 * 64 + ((0 + lhi) ^ sw) * 8);
            ap[1] = *reinterpret_cast<const bf16x8*>(Psw + l15 * 64 + ((4 + lhi) ^ sw) * 8);
            #pragma unroll
            for (int nf = 0; nf < 4; nf++)
                #pragma unroll
                for (int ks2 = 0; ks2 < 2; ks2++) {
                    bf16x8 bv = *reinterpret_cast<const bf16x8*>(
                        Vs0 + cur * 4096 + (nf * 16 + l15) * 64 + ((ks2 * 4 + lhi) ^ sw) * 8);
                    o[nf] = __builtin_amdgcn_mfma_f32_16x16x32_bf16(ap[ks2], bv, o[nf], 0, 0, 0);
                }
            if (kvt < qb) { VMCNT0; __syncthreads(); cur ^= 1; }
        }
        #pragma unroll
        for (int nf = 0; nf < 4; nf++)
            #pragma unroll
            for (int j = 0; j < 4; j++) {
                const int row = q0 + lhi * 4 + j;
                buf[(long)row * LDBUF + h * HDIM + nf * 16 + l15] = f2bf(o[nf][j] / lrow[j]);
            }
    } else if (blockIdx.x < 512) {
        unsigned short* As0 = smem;
        unsigned short* Bs0 = smem + 16384;
        const int b2 = (int)blockIdx.x - 256;
        const int sb = (b2 & 7) * 32 + (b2 >> 3);
        const int kz = sb & 3, nb = (sb >> 2) & 7, mb = sb >> 5;
        const int m0 = mb * 128, n0 = nb * 128;
        const int kt0 = kz * 16;
        const int wr = wid >> 1, wc = wid & 1;
        const unsigned short* Aff = buf + DIM;

        f32x4 acc[4][4];
        #pragma unroll
        for (int i = 0; i < 4; i++)
            #pragma unroll
            for (int j = 0; j < 4; j++) acc[i][j] = (f32x4){0.f, 0.f, 0.f, 0.f};

        auto stage = [&](int bf_, int kt_) {
            const int k0 = kt_ << 6;
            #pragma unroll
            for (int i = 0; i < 4; i++) {
                const int e = (i * 256 + tid) * 8;
                const int r = e >> 6;
                const int cs = (((e >> 3) & 7) ^ (r & 7)) * 8;
                GLD16(Aff + (long)(m0 + r) * LDBUF + k0 + cs, As0 + bf_ * 8192 + i * 2048 + wbase);
                GLD16(fcw + (long)(n0 + r) * FFD + k0 + cs, Bs0 + bf_ * 8192 + i * 2048 + wbase);
            }
        };
        auto compute = [&](int bf_) {
            #pragma unroll
            for (int ks = 0; ks < 2; ks++) {
                bf16x8 af[4], bfr[4];
                #pragma unroll
                for (int mf = 0; mf < 4; mf++)
                    af[mf] = *reinterpret_cast<const bf16x8*>(
                        As0 + bf_ * 8192 + (wr * 64 + mf * 16 + l15) * 64 + ((ks * 4 + lhi) ^ sw) * 8);
                #pragma unroll
                for (int nf = 0; nf < 4; nf++)
                    bfr[nf] = *reinterpret_cast<const bf16x8*>(
                        Bs0 + bf_ * 8192 + (wc * 64 + nf * 16 + l15) * 64 + ((ks * 4 + lhi) ^ sw) * 8);
                #pragma unroll
                for (int mf = 0; mf < 4; mf++)
                    #pragma unroll
                    for (int nf = 0; nf < 4; nf++)
                        acc[mf][nf] = __builtin_amdgcn_mfma_f32_16x16x32_bf16(af[mf], bfr[nf], acc[mf][nf], 0, 0, 0);
            }
        };

        int cur = 0;
        stage(0, kt0);
        VMCNT0; __syncthreads();
        for (int t = 0; t < 16; t++) {
            if (t + 1 < 16) stage(cur ^ 1, kt0 + t + 1);
            compute(cur);
            if (t + 1 < 16) { VMCNT0; __syncthreads(); cur ^= 1; }
        }

        float* P = parts + (long)kz * SQ * DIM;
        #pragma unroll
        for (int nf = 0; nf < 4; nf++) {
            const int col = n0 + wc * 64 + nf * 16 + l15;
            const float bv = (kz == 0) ? fcb[col] : 0.f;
            #pragma unroll
            for (int mf = 0; mf < 4; mf++) {
                #pragma unroll
                for (int j = 0; j < 4; j++) {
                    const int row = m0 + wr * 64 + mf * 16 + lhi * 4 + j;
                    P[(long)row * DIM + col] = acc[mf][nf][j] + bv;
                }
            }
        }
    } else {
        if (nd) {
            const int cb = (int)blockIdx.x - 512;
            const long stride = (long)((int)gridDim.x - 512) * 256;
            const long base = (long)cb * 256 + tid;
            const long n0v = (long)3072 * 1024 / 8, n1v = (long)1024 * 1024 / 8;
            const long n2v = (long)4096 * 1024 / 8, n3v = (long)4096 * 1024 / 8;
            for (long i = base; i < n0v; i += stride) cvt8(nw0, nd, i * 8);
            unsigned short* d1 = nd + n0v * 8;
            for (long i = base; i < n1v; i += stride) cvt8(nw1, d1, i * 8);
            unsigned short* d2 = d1 + n1v * 8;
            for (long i = base; i < n2v; i += stride) cvt8(nw2, d2, i * 8);
            unsigned short* d3 = d2 + n2v * 8;
            for (long i = base; i < n3v; i += stride) cvt8(nw3, d3, i * 8);
        }
    }
}

// ---------------- Wo GEMM (K=1024), split-K=4, RMW into parts[0..3] ----------------
__global__ __launch_bounds__(256) void wo_rmw(const unsigned short* __restrict__ buf,
                                              const unsigned short* __restrict__ wo,
                                              float* __restrict__ parts) {
    __shared__ __align__(16) unsigned short As[2][128 * 64];
    __shared__ __align__(16) unsigned short Bs[2][128 * 64];
    const int tid = threadIdx.x;
    const int sb = (blockIdx.x & 7) * 32 + (blockIdx.x >> 3);
    const int kz = sb & 3, nb = (sb >> 2) & 7, mb = sb >> 5;
    const int m0 = mb * 128, n0 = nb * 128;
    const int kt0 = kz * 4;
    const int lane = tid & 63, wid = tid >> 6;
    const int l15 = lane & 15, lhi = lane >> 4;
    const int wr = wid >> 1, wc = wid & 1;
    const int sw = l15 & 7;
    const int wbase = (tid & ~63) * 8;

    f32x4 acc[4][4];
    #pragma unroll
    for (int i = 0; i < 4; i++)
        #pragma unroll
        for (int j = 0; j < 4; j++) acc[i][j] = (f32x4){0.f, 0.f, 0.f, 0.f};

    auto stage = [&](int bf_, int kt_) {
        const int k0 = kt_ << 6;
        #pragma unroll
        for (int i = 0; i < 4; i++) {
            const int e = (i * 256 + tid) * 8;
            const int r = e >> 6;
            const int cs = (((e >> 3) & 7) ^ (r & 7)) * 8;
            GLD16(buf + (long)(m0 + r) * LDBUF + k0 + cs, &As[bf_][i * 2048 + wbase]);
            GLD16(wo + (long)(n0 + r) * DIM + k0 + cs, &Bs[bf_][i * 2048 + wbase]);
        }
    };
    auto compute = [&](int bf_) {
        #pragma unroll
        for (int ks = 0; ks < 2; ks++) {
            bf16x8 af[4], bfr[4];
            #pragma unroll
            for (int mf = 0; mf < 4; mf++)
                af[mf] = *reinterpret_cast<const bf16x8*>(
                    &As[bf_][(wr * 64 + mf * 16 + l15) * 64 + ((ks * 4 + lhi) ^ sw) * 8]);
            #pragma unroll
            for (int nf = 0; nf < 4; nf++)
                bfr[nf] = *reinterpret_cast<const bf16x8*>(
                    &Bs[bf_][(wc * 64 + nf * 16 + l15) * 64 + ((ks * 4 + lhi) ^ sw) * 8]);
            #pragma unroll
            for (int mf = 0; mf < 4; mf++)
                #pragma unroll
                for (int nf = 0; nf < 4; nf++)
                    acc[mf][nf] = __builtin_amdgcn_mfma_f32_16x16x32_bf16(af[mf], bfr[nf], acc[mf][nf], 0, 0, 0);
        }
    };

    int cur = 0;
    stage(0, kt0);
    VMCNT0; __syncthreads();
    for (int t = 0; t < 4; t++) {
        if (t + 1 < 4) stage(cur ^ 1, kt0 + t + 1);
        compute(cur);
        if (t + 1 < 4) { VMCNT0; __syncthreads(); cur ^= 1; }
    }

    float* P = parts + (long)kz * SQ * DIM;
    #pragma unroll
    for (int nf = 0; nf < 4; nf++) {
        const int col = n0 + wc * 64 + nf * 16 + l15;
        #pragma unroll
        for (int mf = 0; mf < 4; mf++) {
            #pragma unroll
            for (int j = 0; j < 4; j++) {
                const int row = m0 + wr * 64 + mf * 16 + lhi * 4 + j;
                P[(long)row * DIM + col] += acc[mf][nf][j];
            }
        }
    }
}

// ---------------- LM head: 256x256 8-phase (r13/r14 verified: 669 TF) ----------------
__global__ __launch_bounds__(512) void gemm256p8(const unsigned short* __restrict__ A,
                                                 const unsigned short* __restrict__ B,
                                                 const float* __restrict__ bias,
                                                 float* __restrict__ C) {
    __shared__ __align__(16) unsigned short As[2][2][128 * 64];
    __shared__ __align__(16) unsigned short Bs[2][2][128 * 64];
    const int tid = threadIdx.x;
    const int nwg = gridDim.x, qch = nwg >> 3;
    const int sb = (blockIdx.x & 7) * qch + (blockIdx.x >> 3);
    const int mb = sb & 3, nb = sb >> 2;
    const int m0 = mb * 256, n0 = nb * 256;
    const int lane = tid & 63, wid = tid >> 6;
    const int l15 = lane & 15, lhi = lane >> 4;
    const int wm = wid >> 2, wn = wid & 3;
    const int sw = l15 & 7;
    const int wbase = (tid & ~63) * 8;

    f32x4 acc[8][4];
    #pragma unroll
    for (int i = 0; i < 8; i++)
        #pragma unroll
        for (int j = 0; j < 4; j++) acc[i][j] = (f32x4){0.f, 0.f, 0.f, 0.f};

    auto stageA = [&](int kt, int hh) {
        const int k0 = kt << 6;
        unsigned short* dst = &As[kt & 1][hh][0];
        #pragma unroll
        for (int i = 0; i < 2; i++) {
            const int e = (i * 512 + tid) * 8;
            const int r = e >> 6;
            const int cs = (((e >> 3) & 7) ^ (r & 7)) * 8;
            GLD16(A + (long)(m0 + hh * 128 + r) * 1024 + k0 + cs, dst + i * 4096 + wbase);
        }
    };
    auto stageB = [&](int kt, int hh) {
        const int k0 = kt << 6;
        unsigned short* dst = &Bs[kt & 1][hh][0];
        #pragma unroll
        for (int i = 0; i < 2; i++) {
            const int e = (i * 512 + tid) * 8;
            const int r = e >> 6;
            const int cs = (((e >> 3) & 7) ^ (r & 7)) * 8;
            GLD16(B + (long)(n0 + hh * 128 + r) * 1024 + k0 + cs, dst + i * 4096 + wbase);
        }
    };

    bf16x8 afA[4][2], bf0[2][2], bf1[2][2];
    auto ldA = [&](int buf, int hh) {
        #pragma unroll
        for (int mi = 0; mi < 4; mi++) {
            const int row = wm * 64 + mi * 16 + l15;
            #pragma unroll
            for (int ks = 0; ks < 2; ks++)
                afA[mi][ks] = *reinterpret_cast<const bf16x8*>(
                    &As[buf][hh][row * 64 + (((ks * 4 + lhi) ^ sw) * 8)]);
        }
    };
    auto ldB = [&](int buf, int hh, bf16x8 (&bfr)[2][2]) {
        #pragma unroll
        for (int ni = 0; ni < 2; ni++) {
            const int row = wn * 32 + ni * 16 + l15;
            #pragma unroll
            for (int ks = 0; ks < 2; ks++)
                bfr[ni][ks] = *reinterpret_cast<const bf16x8*>(
                    &Bs[buf][hh][row * 64 + (((ks * 4 + lhi) ^ sw) * 8)]);
        }
    };
    auto mfma16 = [&](int mh, int nh, bf16x8 (&bfr)[2][2]) {
        __builtin_amdgcn_s_setprio(1);
        #pragma unroll
        for (int mi = 0; mi < 4; mi++)
            #pragma unroll
            for (int ni = 0; ni < 2; ni++)
                #pragma unroll
                for (int ks = 0; ks < 2; ks++)
                    acc[mh * 4 + mi][nh * 2 + ni] = __builtin_amdgcn_mfma_f32_16x16x32_bf16(
                        afA[mi][ks], bfr[ni][ks], acc[mh * 4 + mi][nh * 2 + ni], 0, 0, 0);
        __builtin_amdgcn_s_setprio(0);
    };

#define BAR()   __builtin_amdgcn_s_barrier()
#define LGKM()  asm volatile("s_waitcnt lgkmcnt(0)" ::: "memory")
#define VM6()   asm volatile("s_waitcnt vmcnt(6)" ::: "memory")

    stageA(0, 0); stageB(0, 0); stageB(0, 1); stageA(0, 1);
    stageA(1, 0); stageB(1, 0); stageB(1, 1);
    VM6();
    BAR();

    for (int it = 0; it < 8; it++) {
        const int e = 2 * it, o = 2 * it + 1;
        const bool more = (it + 1 < 8);
        ldA(0, 0); ldB(0, 0, bf0);
        stageA(o, 1);
        BAR(); LGKM(); mfma16(0, 0, bf0); BAR();
        ldB(0, 1, bf1);
        if (more) stageA(e + 2, 0);
        BAR(); LGKM(); mfma16(0, 1, bf1); BAR();
        ldA(0, 1);
        if (more) stageB(e + 2, 0);
        BAR(); LGKM(); mfma16(1, 1, bf1); BAR();
        if (more) stageB(e + 2, 1);
        if (more) { VM6(); } else { VMCNT0; }
        BAR(); LGKM(); mfma16(1, 0, bf0); BAR();
        ldA(1, 0); ldB(1, 0, bf0);
        if (more) stageA(e + 2, 1);
        BAR(); LGKM(); mfma16(0, 0, bf0); BAR();
        ldB(1, 1, bf1);
        if (more) stageA(o + 2, 0);
        BAR(); LGKM(); mfma16(0, 1, bf1); BAR();
        ldA(1, 1);
        if (more) stageB(o + 2, 0);
        BAR(); LGKM(); mfma16(1, 1, bf1); BAR();
        if (more) { stageB(o + 2, 1); VM6(); }
        BAR(); LGKM(); mfma16(1, 0, bf0); BAR();
    }
#undef BAR
#undef LGKM
#undef VM6

    #pragma unroll
    for (int nf = 0; nf < 4; nf++) {
        const int col = n0 + (nf < 2 ? wn * 32 + nf * 16 : 128 + wn * 32 + (nf - 2) * 16) + l15;
        const float bv = bias[col];
        #pragma unroll
        for (int mf = 0; mf < 8; mf++) {
            const int rowb = m0 + (mf < 4 ? wm * 64 + mf * 16 : 128 + wm * 64 + (mf - 4) * 16) + lhi * 4;
            #pragma unroll
            for (int j = 0; j < 4; j++)
                C[(long)(rowb + j) * NV + col] = acc[mf][nf][j] + bv;
        }
    }
}

extern "C" void kernel_launch(void* const* d_in, const int* in_sizes, int n_in,
                              void* d_out, int out_size, void* d_ws, size_t ws_size,
                              hipStream_t stream) {
    const int* idx    = (const int*)d_in[0];
    const int* pos    = (const int*)d_in[1];
    const float* emb  = (const float*)d_in[2];
    const float* Wqkv = (const float*)d_in[3];
    const float* Wo   = (const float*)d_in[4];
    const float* ln1w = (const float*)d_in[5];
    const float* ln1b = (const float*)d_in[6];
    const float* fciw = (const float*)d_in[7];
    const float* fcib = (const float*)d_in[8];
    const float* fcow = (const float*)d_in[9];
    const float* fcob = (const float*)d_in[10];
    const float* lnfw = (const float*)d_in[11];
    const float* lnfb = (const float*)d_in[12];
    const float* lmw  = (const float*)d_in[13];
    const float* lmb  = (const float*)d_in[14];

    const long tailBytes = (long)SQ * DIM * 4 + (long)4 * SQ * DIM * 4 + (long)SQ * DIM * 2
                         + (long)3 * NH * SQ * HDIM * 2 + (long)SQ * LDBUF * 2 + (long)SQ * 16 * 8;
    const long bigBytes  = 2 * WELEMS * 2 + (long)NV * DIM * 2 + tailBytes;
    const bool big = (long)ws_size >= bigBytes + (1 << 20);

    char* ws = (char*)d_ws;
    unsigned short *wbufA, *wbufB, *lmbuf;
    if (big) {
        wbufA = (unsigned short*)ws; ws += WELEMS * 2;
        wbufB = (unsigned short*)ws; ws += WELEMS * 2;
        lmbuf = (unsigned short*)ws; ws += (long)NV * DIM * 2;
    } else {
        wbufA = (unsigned short*)ws; ws += (long)NV * DIM * 2;
        wbufB = wbufA;
        lmbuf = wbufA;
    }
    float* x           = (float*)ws;          ws += (long)SQ * DIM * 4;
    float* parts       = (float*)ws;          ws += (long)4 * SQ * DIM * 4;
    unsigned short* h  = (unsigned short*)ws; ws += (long)SQ * DIM * 2;
    unsigned short* qt = (unsigned short*)ws; ws += (long)NH * SQ * HDIM * 2;
    unsigned short* kt = (unsigned short*)ws; ws += (long)NH * SQ * HDIM * 2;
    unsigned short* vt = (unsigned short*)ws; ws += (long)NH * SQ * HDIM * 2;
    unsigned short* buf= (unsigned short*)ws; ws += (long)SQ * LDBUF * 2;
    float2* sc         = (float2*)ws;         ws += (long)SQ * 16 * 8;

    auto wq = [&](unsigned short* wb) { return wb; };
    auto wo_ = [&](unsigned short* wb) { return wb + (long)3072 * 1024; };
    auto wfi = [&](unsigned short* wb) { return wb + (long)4096 * 1024; };
    auto wfo = [&](unsigned short* wb) { return wb + (long)8192 * 1024; };

    sincos_kernel<<<64, 256, 0, stream>>>(pos, sc);
    embed_kernel<<<SQ, 256, 0, stream>>>(idx, emb, x);
    cvt4_kernel<<<6144, 256, 0, stream>>>(Wqkv, Wo, fciw, fcow, wbufA);

    for (int l = 0; l < NL; l++) {
        unsigned short* wb = (l & 1) ? wbufB : wbufA;
        unsigned short* wn = (l & 1) ? wbufA : wbufB;

        if (!big && l > 0)
            cvt4_kernel<<<6144, 256, 0, stream>>>(Wqkv + (long)l * 3 * DIM * DIM,
                                                  Wo   + (long)l * DIM * DIM,
                                                  fciw + (long)l * FFD * DIM,
                                                  fcow + (long)l * DIM * FFD, wb);

        if (l == 0) ln_kernel<false><<<SQ, 256, 0, stream>>>(x, nullptr, ln1w, ln1b, h);
        else ln_kernel<true><<<SQ, 256, 0, stream>>>(x, parts, ln1w + (long)l * DIM, ln1b + (long)l * DIM, h);

        gemm_qkv_fcin<<<704, 256, 0, stream>>>(h, wq(wb), wfi(wb), fcib + (long)l * FFD,
                                               buf + DIM, sc, qt, kt, vt,
                                               big ? lmw + (long)l * (NV / NL) * DIM : nullptr,
                                               big ? lmbuf + (long)l * (NV / NL) * DIM : nullptr);
        if (big) {
            const int nl = l + 1;
            attn_fcout<<<1024, 256, 0, stream>>>(qt, kt, vt, buf, wfo(wb),
                                                 fcob + (long)l * DIM, parts,
                                                 (nl < NL) ? Wqkv + (long)nl * 3 * DIM * DIM : nullptr,
                                                 (nl < NL) ? Wo   + (long)nl * DIM * DIM : nullptr,
                                                 (nl < NL) ? fciw + (long)nl * FFD * DIM : nullptr,
                                                 (nl < NL) ? fcow + (long)nl * DIM * FFD : nullptr,
                                                 (nl < NL) ? wn : nullptr);
        } else {
            attn_fcout<<<512, 256, 0, stream>>>(qt, kt, vt, buf, wfo(wb),
                                                fcob + (long)l * DIM, parts,
                                                nullptr, nullptr, nullptr, nullptr, nullptr);
        }
        wo_rmw<<<256, 256, 0, stream>>>(buf, wo_(wb), parts);
    }
    if (!big) cvt_kernel<<<25600, 256, 0, stream>>>(lmw, lmbuf);
    ln_kernel<true><<<SQ, 256, 0, stream>>>(x, parts, lnfw, lnfb, h);
    gemm256p8<<<800, 512, 0, stream>>>(h, lmbuf, lmb, (float*)d_out);
}

// Round 16
// 972.906 us; speedup vs baseline: 1.0435x; 1.0020x over previous
//
#include <hip/hip_runtime.h>

#define SQ 1024
#define DIM 1024
#define NH 16
#define HDIM 64
#define FFD 4096
#define NV 51200
#define NL 8
#define LDBUF 5120
#define WELEMS ((long)(3 * DIM + DIM + FFD + FFD) * DIM)

typedef __bf16 bf16x8 __attribute__((ext_vector_type(8)));
typedef float f32x4 __attribute__((ext_vector_type(4)));

__device__ __forceinline__ unsigned short f2bf(float f) {
    union { float f; unsigned int i; } v; v.f = f;
    unsigned int r = v.i + 0x7fffu + ((v.i >> 16) & 1u);
    return (unsigned short)(r >> 16);
}
__device__ __forceinline__ float gelu_tanh(float x) {
    float x3 = x * x * x;
    return 0.5f * x * (1.0f + tanhf(0.79788456080286535588f * (x + 0.044715f * x3)));
}
__device__ __forceinline__ void cvt8(const float* __restrict__ s, unsigned short* __restrict__ d, long i) {
    float4 a = *reinterpret_cast<const float4*>(s + i);
    float4 b = *reinterpret_cast<const float4*>(s + i + 4);
    bf16x8 w;
    w[0] = (__bf16)a.x; w[1] = (__bf16)a.y; w[2] = (__bf16)a.z; w[3] = (__bf16)a.w;
    w[4] = (__bf16)b.x; w[5] = (__bf16)b.y; w[6] = (__bf16)b.z; w[7] = (__bf16)b.w;
    *reinterpret_cast<bf16x8*>(d + i) = w;
}

#define GLD16(gp, lp) __builtin_amdgcn_global_load_lds( \
    (__attribute__((address_space(1))) void*)(gp), \
    (__attribute__((address_space(3))) void*)(lp), 16, 0, 0)
#define VMCNT0 asm volatile("s_waitcnt vmcnt(0)" ::: "memory")

// ---------------- serial-path weight conversion ----------------
__global__ void cvt4_kernel(const float* __restrict__ w0, const float* __restrict__ w1,
                            const float* __restrict__ w2, const float* __restrict__ w3,
                            unsigned short* __restrict__ dst) {
    const int b = blockIdx.x;
    const float* s; long off; unsigned short* d;
    if (b < 1536)      { s = w0; d = dst;                      off = (long)b * 2048; }
    else if (b < 2048) { s = w1; d = dst + (long)3072 * 1024;  off = (long)(b - 1536) * 2048; }
    else if (b < 4096) { s = w2; d = dst + (long)4096 * 1024;  off = (long)(b - 2048) * 2048; }
    else               { s = w3; d = dst + (long)8192 * 1024;  off = (long)(b - 4096) * 2048; }
    cvt8(s, d, off + threadIdx.x * 8);
}
__global__ void cvt_kernel(const float* __restrict__ src, unsigned short* __restrict__ dst) {
    cvt8(src, dst, ((long)blockIdx.x * 256 + threadIdx.x) * 8);
}

// ---------------- sin/cos table ----------------
__global__ void sincos_kernel(const int* __restrict__ pos, float2* __restrict__ sc) {
    const int t = blockIdx.x * 256 + threadIdx.x;
    if (t >= SQ * 16) return;
    const int s = t >> 4, i = t & 15;
    const float ang = (float)pos[s] * powf(10000.0f, -(float)i / 16.0f);
    sc[t] = make_float2(sinf(ang), cosf(ang));
}

// ---------------- embedding gather ----------------
__global__ void embed_kernel(const int* __restrict__ idx, const float* __restrict__ emb,
                             float* __restrict__ x) {
    const int s = blockIdx.x;
    const int d = threadIdx.x * 4;
    const int row = idx[s];
    *reinterpret_cast<float4*>(x + (long)s * DIM + d) =
        *reinterpret_cast<const float4*>(emb + (long)row * DIM + d);
}

// ---------------- fused (residual reduce over 4 split-K parts) + layernorm ----------------
template <bool RED>
__global__ __launch_bounds__(256) void ln_kernel(float* __restrict__ x,
                                                 const float* __restrict__ part,
                                                 const float* __restrict__ w,
                                                 const float* __restrict__ b,
                                                 unsigned short* __restrict__ out) {
    __shared__ float red[8];
    const int s = blockIdx.x, tid = threadIdx.x;
    const long fidx = (long)s * 256 + tid;
    float4 v = reinterpret_cast<const float4*>(x)[fidx];
    if (RED) {
        #pragma unroll
        for (int z = 0; z < 4; z++) {
            float4 p = reinterpret_cast<const float4*>(part + (long)z * SQ * DIM)[fidx];
            v.x += p.x; v.y += p.y; v.z += p.z; v.w += p.w;
        }
        reinterpret_cast<float4*>(x)[fidx] = v;
    }
    float sum = v.x + v.y + v.z + v.w;
    float sq = v.x * v.x + v.y * v.y + v.z * v.z + v.w * v.w;
    #pragma unroll
    for (int off = 32; off; off >>= 1) { sum += __shfl_xor(sum, off); sq += __shfl_xor(sq, off); }
    const int wid = tid >> 6, lane = tid & 63;
    if (lane == 0) { red[wid * 2] = sum; red[wid * 2 + 1] = sq; }
    __syncthreads();
    sum = red[0] + red[2] + red[4] + red[6];
    sq  = red[1] + red[3] + red[5] + red[7];
    const float mu = sum * (1.0f / DIM);
    const float var = sq * (1.0f / DIM) - mu * mu;
    const float rstd = rsqrtf(var + 1e-5f);
    const int d = tid * 4;
    float vv[4] = {v.x, v.y, v.z, v.w};
    ushort4 o;
    unsigned short* op = (unsigned short*)&o;
    #pragma unroll
    for (int j = 0; j < 4; j++)
        op[j] = f2bf((vv[j] - mu) * rstd * w[d + j] + b[d + j]);
    *reinterpret_cast<ushort4*>(out + (long)s * DIM + d) = o;
}

// ---------------- QKV(+RoPE) + fc_in(gelu) GEMM (0..447) + LM cvt chores (448..703) ----------------
__global__ __launch_bounds__(256) void gemm_qkv_fcin(const unsigned short* __restrict__ A,
                                                     const unsigned short* __restrict__ B1,
                                                     const unsigned short* __restrict__ B2,
                                                     const float* __restrict__ bias,
                                                     unsigned short* __restrict__ ffout,
                                                     const float2* __restrict__ sc,
                                                     unsigned short* __restrict__ qt,
                                                     unsigned short* __restrict__ kt,
                                                     unsigned short* __restrict__ vt,
                                                     const float* __restrict__ lmsrc,
                                                     unsigned short* __restrict__ lmdst) {
    __shared__ __align__(16) unsigned short As[2][128 * 64];
    __shared__ __align__(16) unsigned short Bs[2][128 * 64];
    const int tid = threadIdx.x;
    if (blockIdx.x >= 448) {
        if (lmdst) {
            const int cb = (int)blockIdx.x - 448;
            const long stride = (long)((int)gridDim.x - 448) * 256;
            const long nlmv = (long)(NV / NL) * DIM / 8;
            for (long i = (long)cb * 256 + tid; i < nlmv; i += stride) cvt8(lmsrc, lmdst, i * 8);
        }
        return;
    }
    const int sb = (blockIdx.x & 7) * 56 + (blockIdx.x >> 3);
    const int mb = sb & 7, nb = sb >> 3;
    const int m0 = mb * 128, n0 = nb * 128;
    const int lane = tid & 63, wid = tid >> 6;
    const int l15 = lane & 15, lhi = lane >> 4;
    const int wr = wid >> 1, wc = wid & 1;
    const int sw = l15 & 7;

    const unsigned short* Bbase = B1;
    int nloc = n0;
    if (nb >= 24) { Bbase = B2; nloc = n0 - 3072; }

    f32x4 acc[4][4];
    #pragma unroll
    for (int i = 0; i < 4; i++)
        #pragma unroll
        for (int j = 0; j < 4; j++) acc[i][j] = (f32x4){0.f, 0.f, 0.f, 0.f};

    const int wbase = (tid & ~63) * 8;

    auto stage = [&](int buf, int kt_) {
        const int k0 = kt_ << 6;
        #pragma unroll
        for (int i = 0; i < 4; i++) {
            const int e = (i * 256 + tid) * 8;
            const int r = e >> 6;
            const int cs = (((e >> 3) & 7) ^ (r & 7)) * 8;
            GLD16(A + (long)(m0 + r) * DIM + k0 + cs, &As[buf][i * 2048 + wbase]);
        }
        #pragma unroll
        for (int i = 0; i < 4; i++) {
            const int e = (i * 256 + tid) * 8;
            const int r = e >> 6;
            const int cs = (((e >> 3) & 7) ^ (r & 7)) * 8;
            GLD16(Bbase + (long)(nloc + r) * 1024 + k0 + cs, &Bs[buf][i * 2048 + wbase]);
        }
    };
    auto compute = [&](int buf) {
        #pragma unroll
        for (int ks = 0; ks < 2; ks++) {
            bf16x8 af[4], bfr[4];
            #pragma unroll
            for (int mf = 0; mf < 4; mf++)
                af[mf] = *reinterpret_cast<const bf16x8*>(
                    &As[buf][(wr * 64 + mf * 16 + l15) * 64 + ((ks * 4 + lhi) ^ sw) * 8]);
            #pragma unroll
            for (int nf = 0; nf < 4; nf++)
                bfr[nf] = *reinterpret_cast<const bf16x8*>(
                    &Bs[buf][(wc * 64 + nf * 16 + l15) * 64 + ((ks * 4 + lhi) ^ sw) * 8]);
            #pragma unroll
            for (int mf = 0; mf < 4; mf++)
                #pragma unroll
                for (int nf = 0; nf < 4; nf++)
                    acc[mf][nf] = __builtin_amdgcn_mfma_f32_16x16x32_bf16(af[mf], bfr[nf], acc[mf][nf], 0, 0, 0);
        }
    };

    int cur = 0;
    stage(0, 0);
    VMCNT0; __syncthreads();
    for (int kt_ = 0; kt_ < 16; kt_++) {
        if (kt_ + 1 < 16) stage(cur ^ 1, kt_ + 1);
        compute(cur);
        if (kt_ + 1 < 16) { VMCNT0; __syncthreads(); cur ^= 1; }
    }

    if (nb < 24) {
        #pragma unroll
        for (int nf = 0; nf < 4; nf++) {
            const int col = n0 + wc * 64 + nf * 16 + l15;
            const int g = col / 768;
            const int r768 = col - g * 768;
            const int sec = r768 >> 8;
            const int off = r768 & 255;
            const int h = g * 4 + (off >> 6);
            const int d = off & 63;
            const bool isrot = (d < 32);
            const int dodd = d & 1;
            #pragma unroll
            for (int mf = 0; mf < 4; mf++) {
                #pragma unroll
                for (int j = 0; j < 4; j++) {
                    const int row = m0 + wr * 64 + mf * 16 + lhi * 4 + j;
                    float v = acc[mf][nf][j];
                    const float pv = __shfl_xor(v, 1);
                    float outv = v;
                    if (isrot && sec != 1) {
                        const float2 scv = sc[row * 16 + (d >> 1)];
                        outv = dodd ? (v * scv.y + pv * scv.x)
                                    : (v * scv.y - pv * scv.x);
                    }
                    if (sec == 0)      qt[((long)(h * SQ + row)) * HDIM + d] = f2bf(outv);
                    else if (sec == 2) kt[((long)(h * SQ + row)) * HDIM + d] = f2bf(outv);
                    else               vt[(long)h * (HDIM * SQ) + (long)d * SQ + row] = f2bf(outv);
                }
            }
        }
    } else {
        #pragma unroll
        for (int nf = 0; nf < 4; nf++) {
            const int col = n0 + wc * 64 + nf * 16 + l15;
            #pragma unroll
            for (int mf = 0; mf < 4; mf++) {
                #pragma unroll
                for (int j = 0; j < 4; j++) {
                    const int row = m0 + wr * 64 + mf * 16 + lhi * 4 + j;
                    float v = gelu_tanh(acc[mf][nf][j] + bias[col - 3072]);
                    ffout[(long)row * LDBUF + (col - 3072)] = f2bf(v);
                }
            }
        }
    }
}

// ---------------- FUSED: attention (0..255, STAGED dbuf — r13 verified) + fc_out split-K4 (256..511)
//                  + weight chores (512..) ----------------
// r14 lesson: L2-direct attn regressed ~38us — global_load_lds dbuf is the latency-hiding
// pipeline (prefetch tile t+1 during tile t MFMA), not a reuse cache. Reverted to r13.
__global__ __launch_bounds__(256) void attn_fcout(const unsigned short* __restrict__ qt,
                                                  const unsigned short* __restrict__ kt,
                                                  const unsigned short* __restrict__ vt,
                                                  unsigned short* __restrict__ buf,
                                                  const unsigned short* __restrict__ fcw,
                                                  const float* __restrict__ fcb,
                                                  float* __restrict__ parts,
                                                  const float* __restrict__ nw0,
                                                  const float* __restrict__ nw1,
                                                  const float* __restrict__ nw2,
                                                  const float* __restrict__ nw3,
                                                  unsigned short* __restrict__ nd) {
    __shared__ __align__(16) unsigned short smem[32768];
    const int tid = threadIdx.x, lane = tid & 63, wid = tid >> 6;
    const int l15 = lane & 15, lhi = lane >> 4;
    const int sw = l15 & 7;
    const int wbase = (tid & ~63) * 8;

    if (blockIdx.x < 256) {
        unsigned short* Ks0 = smem;
        unsigned short* Vs0 = smem + 8192;
        unsigned short* Psw = smem + 16384 + wid * 1024;
        const int h = blockIdx.x & 15;
        const int qb = 15 - ((int)blockIdx.x >> 4);
        const int q0 = qb * 64 + wid * 16;

        bf16x8 aq[2];
        {
            const unsigned short* qp = qt + ((long)(h * SQ + q0 + l15)) * HDIM;
            aq[0] = *reinterpret_cast<const bf16x8*>(qp + lhi * 8);
            aq[1] = *reinterpret_cast<const bf16x8*>(qp + 32 + lhi * 8);
        }
        f32x4 o[4];
        #pragma unroll
        for (int nf = 0; nf < 4; nf++) o[nf] = (f32x4){0.f, 0.f, 0.f, 0.f};
        float mrow[4] = {-1e30f, -1e30f, -1e30f, -1e30f};
        float lrow[4] = {0.f, 0.f, 0.f, 0.f};

        auto stageKV = [&](int b, int kv0) {
            #pragma unroll
            for (int i = 0; i < 2; i++) {
                const int e = (i * 256 + tid) * 8;
                const int r = e >> 6;
                const int cs = (((e >> 3) & 7) ^ (r & 7)) * 8;
                GLD16(kt + ((long)(h * SQ + kv0 + r)) * HDIM + cs, Ks0 + b * 4096 + i * 2048 + wbase);
                GLD16(vt + (long)h * (HDIM * SQ) + (long)r * SQ + kv0 + cs, Vs0 + b * 4096 + i * 2048 + wbase);
            }
        };

        int cur = 0;
        stageKV(0, 0);
        VMCNT0; __syncthreads();
        for (int kvt = 0; kvt <= qb; kvt++) {
            const int kv0 = kvt * 64;
            if (kvt < qb) stageKV(cur ^ 1, kv0 + 64);

            f32x4 sa[4];
            #pragma unroll
            for (int hc = 0; hc < 4; hc++) sa[hc] = (f32x4){0.f, 0.f, 0.f, 0.f};
            #pragma unroll
            for (int hc = 0; hc < 4; hc++)
                #pragma unroll
                for (int ks = 0; ks < 2; ks++) {
                    bf16x8 bk = *reinterpret_cast<const bf16x8*>(
                        Ks0 + cur * 4096 + (hc * 16 + l15) * 64 + ((ks * 4 + lhi) ^ sw) * 8);
                    sa[hc] = __builtin_amdgcn_mfma_f32_16x16x32_bf16(aq[ks], bk, sa[hc], 0, 0, 0);
                }
            float pr[4][4], mb[4];
            #pragma unroll
            for (int j = 0; j < 4; j++) {
                const int qi = q0 + lhi * 4 + j;
                #pragma unroll
                for (int hc = 0; hc < 4; hc++) {
                    const int ki = kv0 + hc * 16 + l15;
                    const float sv = sa[hc][j] * 0.125f;
                    pr[hc][j] = (ki <= qi) ? sv : -1e30f;
                }
                mb[j] = fmaxf(fmaxf(pr[0][j], pr[1][j]), fmaxf(pr[2][j], pr[3][j]));
            }
            #pragma unroll
            for (int off = 1; off < 16; off <<= 1)
                #pragma unroll
                for (int j = 0; j < 4; j++) mb[j] = fmaxf(mb[j], __shfl_xor(mb[j], off));
            float alpha[4], psum[4];
            #pragma unroll
            for (int j = 0; j < 4; j++) {
                const float mn = fmaxf(mrow[j], mb[j]);
                alpha[j] = __expf(mrow[j] - mn);
                mrow[j] = mn;
                psum[j] = 0.f;
                #pragma unroll
                for (int hc = 0; hc < 4; hc++) { pr[hc][j] = __expf(pr[hc][j] - mn); psum[j] += pr[hc][j]; }
            }
            #pragma unroll
            for (int off = 1; off < 16; off <<= 1)
                #pragma unroll
                for (int j = 0; j < 4; j++) psum[j] += __shfl_xor(psum[j], off);
            #pragma unroll
            for (int j = 0; j < 4; j++) lrow[j] = lrow[j] * alpha[j] + psum[j];
            #pragma unroll
            for (int nf = 0; nf < 4; nf++)
                #pragma unroll
                for (int j = 0; j < 4; j++) o[nf][j] *= alpha[j];
            #pragma unroll
            for (int hc = 0; hc < 4; hc++)
                #pragma unroll
                for (int j = 0; j < 4; j++) {
                    const int prow = lhi * 4 + j;
                    const int pc8 = (hc * 2 + (l15 >> 3)) ^ (prow & 7);
                    Psw[prow * 64 + pc8 * 8 + (l15 & 7)] = f2bf(pr[hc][j]);
                }
            bf16x8 ap[2];
            ap[0] = *reinterpret_cast<const bf16x8*>(Psw + l15 * 64 + ((0 + lhi) ^ sw) * 8);
            ap[1] = *reinterpret_cast<const bf16x8*>(Psw + l15 * 64 + ((4 + lhi) ^ sw) * 8);
            #pragma unroll
            for (int nf = 0; nf < 4; nf++)
                #pragma unroll
                for (int ks2 = 0; ks2 < 2; ks2++) {
                    bf16x8 bv = *reinterpret_cast<const bf16x8*>(
                        Vs0 + cur * 4096 + (nf * 16 + l15) * 64 + ((ks2 * 4 + lhi) ^ sw) * 8);
                    o[nf] = __builtin_amdgcn_mfma_f32_16x16x32_bf16(ap[ks2], bv, o[nf], 0, 0, 0);
                }
            if (kvt < qb) { VMCNT0; __syncthreads(); cur ^= 1; }
        }
        #pragma unroll
        for (int nf = 0; nf < 4; nf++)
            #pragma unroll
            for (int j = 0; j < 4; j++) {
                const int row = q0 + lhi * 4 + j;
                buf[(long)row * LDBUF + h * HDIM + nf * 16 + l15] = f2bf(o[nf][j] / lrow[j]);
            }
    } else if (blockIdx.x < 512) {
        unsigned short* As0 = smem;
        unsigned short* Bs0 = smem + 16384;
        const int b2 = (int)blockIdx.x - 256;
        const int sb = (b2 & 7) * 32 + (b2 >> 3);
        const int kz = sb & 3, nb = (sb >> 2) & 7, mb = sb >> 5;
        const int m0 = mb * 128, n0 = nb * 128;
        const int kt0 = kz * 16;
        const int wr = wid >> 1, wc = wid & 1;
        const unsigned short* Aff = buf + DIM;

        f32x4 acc[4][4];
        #pragma unroll
        for (int i = 0; i < 4; i++)
            #pragma unroll
            for (int j = 0; j < 4; j++) acc[i][j] = (f32x4){0.f, 0.f, 0.f, 0.f};

        auto stage = [&](int bf_, int kt_) {
            const int k0 = kt_ << 6;
            #pragma unroll
            for (int i = 0; i < 4; i++) {
                const int e = (i * 256 + tid) * 8;
                const int r = e >> 6;
                const int cs = (((e >> 3) & 7) ^ (r & 7)) * 8;
                GLD16(Aff + (long)(m0 + r) * LDBUF + k0 + cs, As0 + bf_ * 8192 + i * 2048 + wbase);
                GLD16(fcw + (long)(n0 + r) * FFD + k0 + cs, Bs0 + bf_ * 8192 + i * 2048 + wbase);
            }
        };
        auto compute = [&](int bf_) {
            #pragma unroll
            for (int ks = 0; ks < 2; ks++) {
                bf16x8 af[4], bfr[4];
                #pragma unroll
                for (int mf = 0; mf < 4; mf++)
                    af[mf] = *reinterpret_cast<const bf16x8*>(
                        As0 + bf_ * 8192 + (wr * 64 + mf * 16 + l15) * 64 + ((ks * 4 + lhi) ^ sw) * 8);
                #pragma unroll
                for (int nf = 0; nf < 4; nf++)
                    bfr[nf] = *reinterpret_cast<const bf16x8*>(
                        Bs0 + bf_ * 8192 + (wc * 64 + nf * 16 + l15) * 64 + ((ks * 4 + lhi) ^ sw) * 8);
                #pragma unroll
                for (int mf = 0; mf < 4; mf++)
                    #pragma unroll
                    for (int nf = 0; nf < 4; nf++)
                        acc[mf][nf] = __builtin_amdgcn_mfma_f32_16x16x32_bf16(af[mf], bfr[nf], acc[mf][nf], 0, 0, 0);
            }
        };

        int cur = 0;
        stage(0, kt0);
        VMCNT0; __syncthreads();
        for (int t = 0; t < 16; t++) {
            if (t + 1 < 16) stage(cur ^ 1, kt0 + t + 1);
            compute(cur);
            if (t + 1 < 16) { VMCNT0; __syncthreads(); cur ^= 1; }
        }

        float* P = parts + (long)kz * SQ * DIM;
        #pragma unroll
        for (int nf = 0; nf < 4; nf++) {
            const int col = n0 + wc * 64 + nf * 16 + l15;
            const float bv = (kz == 0) ? fcb[col] : 0.f;
            #pragma unroll
            for (int mf = 0; mf < 4; mf++) {
                #pragma unroll
                for (int j = 0; j < 4; j++) {
                    const int row = m0 + wr * 64 + mf * 16 + lhi * 4 + j;
                    P[(long)row * DIM + col] = acc[mf][nf][j] + bv;
                }
            }
        }
    } else {
        if (nd) {
            const int cb = (int)blockIdx.x - 512;
            const long stride = (long)((int)gridDim.x - 512) * 256;
            const long base = (long)cb * 256 + tid;
            const long n0v = (long)3072 * 1024 / 8, n1v = (long)1024 * 1024 / 8;
            const long n2v = (long)4096 * 1024 / 8, n3v = (long)4096 * 1024 / 8;
            for (long i = base; i < n0v; i += stride) cvt8(nw0, nd, i * 8);
            unsigned short* d1 = nd + n0v * 8;
            for (long i = base; i < n1v; i += stride) cvt8(nw1, d1, i * 8);
            unsigned short* d2 = d1 + n1v * 8;
            for (long i = base; i < n2v; i += stride) cvt8(nw2, d2, i * 8);
            unsigned short* d3 = d2 + n2v * 8;
            for (long i = base; i < n3v; i += stride) cvt8(nw3, d3, i * 8);
        }
    }
}

// ---------------- Wo GEMM (K=1024), split-K=4, RMW into parts[0..3] ----------------
__global__ __launch_bounds__(256) void wo_rmw(const unsigned short* __restrict__ buf,
                                              const unsigned short* __restrict__ wo,
                                              float* __restrict__ parts) {
    __shared__ __align__(16) unsigned short As[2][128 * 64];
    __shared__ __align__(16) unsigned short Bs[2][128 * 64];
    const int tid = threadIdx.x;
    const int sb = (blockIdx.x & 7) * 32 + (blockIdx.x >> 3);
    const int kz = sb & 3, nb = (sb >> 2) & 7, mb = sb >> 5;
    const int m0 = mb * 128, n0 = nb * 128;
    const int kt0 = kz * 4;
    const int lane = tid & 63, wid = tid >> 6;
    const int l15 = lane & 15, lhi = lane >> 4;
    const int wr = wid >> 1, wc = wid & 1;
    const int sw = l15 & 7;
    const int wbase = (tid & ~63) * 8;

    f32x4 acc[4][4];
    #pragma unroll
    for (int i = 0; i < 4; i++)
        #pragma unroll
        for (int j = 0; j < 4; j++) acc[i][j] = (f32x4){0.f, 0.f, 0.f, 0.f};

    auto stage = [&](int bf_, int kt_) {
        const int k0 = kt_ << 6;
        #pragma unroll
        for (int i = 0; i < 4; i++) {
            const int e = (i * 256 + tid) * 8;
            const int r = e >> 6;
            const int cs = (((e >> 3) & 7) ^ (r & 7)) * 8;
            GLD16(buf + (long)(m0 + r) * LDBUF + k0 + cs, &As[bf_][i * 2048 + wbase]);
            GLD16(wo + (long)(n0 + r) * DIM + k0 + cs, &Bs[bf_][i * 2048 + wbase]);
        }
    };
    auto compute = [&](int bf_) {
        #pragma unroll
        for (int ks = 0; ks < 2; ks++) {
            bf16x8 af[4], bfr[4];
            #pragma unroll
            for (int mf = 0; mf < 4; mf++)
                af[mf] = *reinterpret_cast<const bf16x8*>(
                    &As[bf_][(wr * 64 + mf * 16 + l15) * 64 + ((ks * 4 + lhi) ^ sw) * 8]);
            #pragma unroll
            for (int nf = 0; nf < 4; nf++)
                bfr[nf] = *reinterpret_cast<const bf16x8*>(
                    &Bs[bf_][(wc * 64 + nf * 16 + l15) * 64 + ((ks * 4 + lhi) ^ sw) * 8]);
            #pragma unroll
            for (int mf = 0; mf < 4; mf++)
                #pragma unroll
                for (int nf = 0; nf < 4; nf++)
                    acc[mf][nf] = __builtin_amdgcn_mfma_f32_16x16x32_bf16(af[mf], bfr[nf], acc[mf][nf], 0, 0, 0);
        }
    };

    int cur = 0;
    stage(0, kt0);
    VMCNT0; __syncthreads();
    for (int t = 0; t < 4; t++) {
        if (t + 1 < 4) stage(cur ^ 1, kt0 + t + 1);
        compute(cur);
        if (t + 1 < 4) { VMCNT0; __syncthreads(); cur ^= 1; }
    }

    float* P = parts + (long)kz * SQ * DIM;
    #pragma unroll
    for (int nf = 0; nf < 4; nf++) {
        const int col = n0 + wc * 64 + nf * 16 + l15;
        #pragma unroll
        for (int mf = 0; mf < 4; mf++) {
            #pragma unroll
            for (int j = 0; j < 4; j++) {
                const int row = m0 + wr * 64 + mf * 16 + lhi * 4 + j;
                P[(long)row * DIM + col] += acc[mf][nf][j];
            }
        }
    }
}

// ---------------- LM head: 256x256 8-phase (r13/r14 verified: 669 TF) ----------------
__global__ __launch_bounds__(512) void gemm256p8(const unsigned short* __restrict__ A,
                                                 const unsigned short* __restrict__ B,
                                                 const float* __restrict__ bias,
                                                 float* __restrict__ C) {
    __shared__ __align__(16) unsigned short As[2][2][128 * 64];
    __shared__ __align__(16) unsigned short Bs[2][2][128 * 64];
    const int tid = threadIdx.x;
    const int nwg = gridDim.x, qch = nwg >> 3;
    const int sb = (blockIdx.x & 7) * qch + (blockIdx.x >> 3);
    const int mb = sb & 3, nb = sb >> 2;
    const int m0 = mb * 256, n0 = nb * 256;
    const int lane = tid & 63, wid = tid >> 6;
    const int l15 = lane & 15, lhi = lane >> 4;
    const int wm = wid >> 2, wn = wid & 3;
    const int sw = l15 & 7;
    const int wbase = (tid & ~63) * 8;

    f32x4 acc[8][4];
    #pragma unroll
    for (int i = 0; i < 8; i++)
        #pragma unroll
        for (int j = 0; j < 4; j++) acc[i][j] = (f32x4){0.f, 0.f, 0.f, 0.f};

    auto stageA = [&](int kt, int hh) {
        const int k0 = kt << 6;
        unsigned short* dst = &As[kt & 1][hh][0];
        #pragma unroll
        for (int i = 0; i < 2; i++) {
            const int e = (i * 512 + tid) * 8;
            const int r = e >> 6;
            const int cs = (((e >> 3) & 7) ^ (r & 7)) * 8;
            GLD16(A + (long)(m0 + hh * 128 + r) * 1024 + k0 + cs, dst + i * 4096 + wbase);
        }
    };
    auto stageB = [&](int kt, int hh) {
        const int k0 = kt << 6;
        unsigned short* dst = &Bs[kt & 1][hh][0];
        #pragma unroll
        for (int i = 0; i < 2; i++) {
            const int e = (i * 512 + tid) * 8;
            const int r = e >> 6;
            const int cs = (((e >> 3) & 7) ^ (r & 7)) * 8;
            GLD16(B + (long)(n0 + hh * 128 + r) * 1024 + k0 + cs, dst + i * 4096 + wbase);
        }
    };

    bf16x8 afA[4][2], bf0[2][2], bf1[2][2];
    auto ldA = [&](int buf, int hh) {
        #pragma unroll
        for (int mi = 0; mi < 4; mi++) {
            const int row = wm * 64 + mi * 16 + l15;
            #pragma unroll
            for (int ks = 0; ks < 2; ks++)
                afA[mi][ks] = *reinterpret_cast<const bf16x8*>(
                    &As[buf][hh][row * 64 + (((ks * 4 + lhi) ^ sw) * 8)]);
        }
    };
    auto ldB = [&](int buf, int hh, bf16x8 (&bfr)[2][2]) {
        #pragma unroll
        for (int ni = 0; ni < 2; ni++) {
            const int row = wn * 32 + ni * 16 + l15;
            #pragma unroll
            for (int ks = 0; ks < 2; ks++)
                bfr[ni][ks] = *reinterpret_cast<const bf16x8*>(
                    &Bs[buf][hh][row * 64 + (((ks * 4 + lhi) ^ sw) * 8)]);
        }
    };
    auto mfma16 = [&](int mh, int nh, bf16x8 (&bfr)[2][2]) {
        __builtin_amdgcn_s_setprio(1);
        #pragma unroll
        for (int mi = 0; mi < 4; mi++)
            #pragma unroll
            for (int ni = 0; ni < 2; ni++)
                #pragma unroll
                for (int ks = 0; ks < 2; ks++)
                    acc[mh * 4 + mi][nh * 2 + ni] = __builtin_amdgcn_mfma_f32_16x16x32_bf16(
                        afA[mi][ks], bfr[ni][ks], acc[mh * 4 + mi][nh * 2 + ni], 0, 0, 0);
        __builtin_amdgcn_s_setprio(0);
    };

#define BAR()   __builtin_amdgcn_s_barrier()
#define LGKM()  asm volatile("s_waitcnt lgkmcnt(0)" ::: "memory")
#define VM6()   asm volatile("s_waitcnt vmcnt(6)" ::: "memory")

    stageA(0, 0); stageB(0, 0); stageB(0, 1); stageA(0, 1);
    stageA(1, 0); stageB(1, 0); stageB(1, 1);
    VM6();
    BAR();

    for (int it = 0; it < 8; it++) {
        const int e = 2 * it, o = 2 * it + 1;
        const bool more = (it + 1 < 8);
        ldA(0, 0); ldB(0, 0, bf0);
        stageA(o, 1);
        BAR(); LGKM(); mfma16(0, 0, bf0); BAR();
        ldB(0, 1, bf1);
        if (more) stageA(e + 2, 0);
        BAR(); LGKM(); mfma16(0, 1, bf1); BAR();
        ldA(0, 1);
        if (more) stageB(e + 2, 0);
        BAR(); LGKM(); mfma16(1, 1, bf1); BAR();
        if (more) stageB(e + 2, 1);
        if (more) { VM6(); } else { VMCNT0; }
        BAR(); LGKM(); mfma16(1, 0, bf0); BAR();
        ldA(1, 0); ldB(1, 0, bf0);
        if (more) stageA(e + 2, 1);
        BAR(); LGKM(); mfma16(0, 0, bf0); BAR();
        ldB(1, 1, bf1);
        if (more) stageA(o + 2, 0);
        BAR(); LGKM(); mfma16(0, 1, bf1); BAR();
        ldA(1, 1);
        if (more) stageB(o + 2, 0);
        BAR(); LGKM(); mfma16(1, 1, bf1); BAR();
        if (more) { stageB(o + 2, 1); VM6(); }
        BAR(); LGKM(); mfma16(1, 0, bf0); BAR();
    }
#undef BAR
#undef LGKM
#undef VM6

    #pragma unroll
    for (int nf = 0; nf < 4; nf++) {
        const int col = n0 + (nf < 2 ? wn * 32 + nf * 16 : 128 + wn * 32 + (nf - 2) * 16) + l15;
        const float bv = bias[col];
        #pragma unroll
        for (int mf = 0; mf < 8; mf++) {
            const int rowb = m0 + (mf < 4 ? wm * 64 + mf * 16 : 128 + wm * 64 + (mf - 4) * 16) + lhi * 4;
            #pragma unroll
            for (int j = 0; j < 4; j++)
                C[(long)(rowb + j) * NV + col] = acc[mf][nf][j] + bv;
        }
    }
}

extern "C" void kernel_launch(void* const* d_in, const int* in_sizes, int n_in,
                              void* d_out, int out_size, void* d_ws, size_t ws_size,
                              hipStream_t stream) {
    const int* idx    = (const int*)d_in[0];
    const int* pos    = (const int*)d_in[1];
    const float* emb  = (const float*)d_in[2];
    const float* Wqkv = (const float*)d_in[3];
    const float* Wo   = (const float*)d_in[4];
    const float* ln1w = (const float*)d_in[5];
    const float* ln1b = (const float*)d_in[6];
    const float* fciw = (const float*)d_in[7];
    const float* fcib = (const float*)d_in[8];
    const float* fcow = (const float*)d_in[9];
    const float* fcob = (const float*)d_in[10];
    const float* lnfw = (const float*)d_in[11];
    const float* lnfb = (const float*)d_in[12];
    const float* lmw  = (const float*)d_in[13];
    const float* lmb  = (const float*)d_in[14];

    const long tailBytes = (long)SQ * DIM * 4 + (long)4 * SQ * DIM * 4 + (long)SQ * DIM * 2
                         + (long)3 * NH * SQ * HDIM * 2 + (long)SQ * LDBUF * 2 + (long)SQ * 16 * 8;
    const long bigBytes  = 2 * WELEMS * 2 + (long)NV * DIM * 2 + tailBytes;
    const bool big = (long)ws_size >= bigBytes + (1 << 20);

    char* ws = (char*)d_ws;
    unsigned short *wbufA, *wbufB, *lmbuf;
    if (big) {
        wbufA = (unsigned short*)ws; ws += WELEMS * 2;
        wbufB = (unsigned short*)ws; ws += WELEMS * 2;
        lmbuf = (unsigned short*)ws; ws += (long)NV * DIM * 2;
    } else {
        wbufA = (unsigned short*)ws; ws += (long)NV * DIM * 2;
        wbufB = wbufA;
        lmbuf = wbufA;
    }
    float* x           = (float*)ws;          ws += (long)SQ * DIM * 4;
    float* parts       = (float*)ws;          ws += (long)4 * SQ * DIM * 4;
    unsigned short* h  = (unsigned short*)ws; ws += (long)SQ * DIM * 2;
    unsigned short* qt = (unsigned short*)ws; ws += (long)NH * SQ * HDIM * 2;
    unsigned short* kt = (unsigned short*)ws; ws += (long)NH * SQ * HDIM * 2;
    unsigned short* vt = (unsigned short*)ws; ws += (long)NH * SQ * HDIM * 2;
    unsigned short* buf= (unsigned short*)ws; ws += (long)SQ * LDBUF * 2;
    float2* sc         = (float2*)ws;         ws += (long)SQ * 16 * 8;

    auto wq = [&](unsigned short* wb) { return wb; };
    auto wo_ = [&](unsigned short* wb) { return wb + (long)3072 * 1024; };
    auto wfi = [&](unsigned short* wb) { return wb + (long)4096 * 1024; };
    auto wfo = [&](unsigned short* wb) { return wb + (long)8192 * 1024; };

    sincos_kernel<<<64, 256, 0, stream>>>(pos, sc);
    embed_kernel<<<SQ, 256, 0, stream>>>(idx, emb, x);
    cvt4_kernel<<<6144, 256, 0, stream>>>(Wqkv, Wo, fciw, fcow, wbufA);

    for (int l = 0; l < NL; l++) {
        unsigned short* wb = (l & 1) ? wbufB : wbufA;
        unsigned short* wn = (l & 1) ? wbufA : wbufB;

        if (!big && l > 0)
            cvt4_kernel<<<6144, 256, 0, stream>>>(Wqkv + (long)l * 3 * DIM * DIM,
                                                  Wo   + (long)l * DIM * DIM,
                                                  fciw + (long)l * FFD * DIM,
                                                  fcow + (long)l * DIM * FFD, wb);

        if (l == 0) ln_kernel<false><<<SQ, 256, 0, stream>>>(x, nullptr, ln1w, ln1b, h);
        else ln_kernel<true><<<SQ, 256, 0, stream>>>(x, parts, ln1w + (long)l * DIM, ln1b + (long)l * DIM, h);

        gemm_qkv_fcin<<<704, 256, 0, stream>>>(h, wq(wb), wfi(wb), fcib + (long)l * FFD,
                                               buf + DIM, sc, qt, kt, vt,
                                               big ? lmw + (long)l * (NV / NL) * DIM : nullptr,
                                               big ? lmbuf + (long)l * (NV / NL) * DIM : nullptr);
        if (big) {
            const int nl = l + 1;
            attn_fcout<<<1024, 256, 0, stream>>>(qt, kt, vt, buf, wfo(wb),
                                                 fcob + (long)l * DIM, parts,
                                                 (nl < NL) ? Wqkv + (long)nl * 3 * DIM * DIM : nullptr,
                                                 (nl < NL) ? Wo   + (long)nl * DIM * DIM : nullptr,
                                                 (nl < NL) ? fciw + (long)nl * FFD * DIM : nullptr,
                                                 (nl < NL) ? fcow + (long)nl * DIM * FFD : nullptr,
                                                 (nl < NL) ? wn : nullptr);
        } else {
            attn_fcout<<<512, 256, 0, stream>>>(qt, kt, vt, buf, wfo(wb),
                                                fcob + (long)l * DIM, parts,
                                                nullptr, nullptr, nullptr, nullptr, nullptr);
        }
        wo_rmw<<<256, 256, 0, stream>>>(buf, wo_(wb), parts);
    }
    if (!big) cvt_kernel<<<25600, 256, 0, stream>>>(lmw, lmbuf);
    ln_kernel<true><<<SQ, 256, 0, stream>>>(x, parts, lnfw, lnfb, h);
    gemm256p8<<<800, 512, 0, stream>>>(h, lmbuf, lmb, (float*)d_out);
}